// Round 4
// baseline (561.174 us; speedup 1.0000x reference)
//
#include <hip/hip_runtime.h>
#include <hip/hip_cooperative_groups.h>

namespace cg = cooperative_groups;

#define N_NODES 50000
#define N_EDGES 800000
#define KPTS 15
#define IN_DIM 32
#define OUT_DIM 64
#define KP_EXTENT 0.6f
#define INV_EXT (1.0f / KP_EXTENT)
#define EXT2 (KP_EXTENT * KP_EXTENT)

#define CAP 131072          // per-k list capacity (expected ~13k/k, 10x margin)
#define CNT_STRIDE 64       // ints: 256B between counters -> distinct L2 channels
#define EDGE_TILES (N_EDGES / 256)   // 3125 tiles of 256 edges
#define GRID_BLOCKS 1024    // 4 blocks/CU * 256 CUs -> co-resident by launch_bounds

// ws layout:
//   [0,        4096)  per-k counters (padded, CNT_STRIDE)
//   [4096,   204096)  pcnt[50000] slot counters
//   [262144, ~16MB )  15 lists of CAP uint2  (sd, d2-bits)
//   [16MB,   ...   )  slots[50000][scap][64] fp32 partial rows
#define PCNT_OFF 4096
#define LIST_OFF 262144
#define SLOT_OFF 16777216
#define SCAP_MAX 8

// ===========================================================================
// Fused cooperative kernel: zero -> geometry/compact -> pair matmul -> reduce
// ===========================================================================
__global__ __launch_bounds__(256, 4) void kpconv_fused(
    const float* __restrict__ pos,
    const float* __restrict__ feat,
    const float* __restrict__ kp,
    const float* __restrict__ W,       // [15][32][64]
    const int*   __restrict__ esrc,
    const int*   __restrict__ edst,
    int*         __restrict__ cnt,
    int*         __restrict__ pcnt,
    uint2*       __restrict__ lists,
    float*       __restrict__ slots,
    float*       __restrict__ out,
    const int scap)
{
    cg::grid_group grid = cg::this_grid();

    const int tid  = threadIdx.x;
    const int wv   = tid >> 6;
    const int lane = tid & 63;
    const int nb   = gridDim.x;
    const int gid  = blockIdx.x * 256 + tid;
    const int gsz  = nb * 256;

    // ---- phase 0: zero out / pcnt / cnt --------------------------------
    {
        float4* outz = (float4*)out;
        for (int i = gid; i < (N_NODES * OUT_DIM) / 4; i += gsz)
            outz[i] = make_float4(0.0f, 0.0f, 0.0f, 0.0f);
        for (int i = gid; i < N_NODES; i += gsz)
            pcnt[i] = 0;
        if (gid < KPTS)
            cnt[gid * CNT_STRIDE] = 0;
    }
    grid.sync();

    // ---- phase 1: geometry + ballot compaction -------------------------
    {
        __shared__ int s_wavecnt[KPTS][4];
        __shared__ int s_woff[KPTS][4];
        __shared__ int s_base[KPTS];

        float kxv[KPTS], kyv[KPTS], kzv[KPTS];
        #pragma unroll
        for (int k = 0; k < KPTS; ++k) {
            kxv[k] = kp[k * 3 + 0];
            kyv[k] = kp[k * 3 + 1];
            kzv[k] = kp[k * 3 + 2];
        }

        for (int tile = blockIdx.x; tile < EDGE_TILES; tile += nb) {
            const int e = tile * 256 + tid;
            const int s = esrc[e];
            const int d = edst[e];

            const float yx = pos[s * 3 + 0] - pos[d * 3 + 0];
            const float yy = pos[s * 3 + 1] - pos[d * 3 + 1];
            const float yz = pos[s * 3 + 2] - pos[d * 3 + 2];

            float d2v[KPTS];
            unsigned act = 0;
            #pragma unroll
            for (int k = 0; k < KPTS; ++k) {
                const float dx = yx - kxv[k];
                const float dy = yy - kyv[k];
                const float dz = yz - kzv[k];
                const float d2 = dx * dx + dy * dy + dz * dz;
                d2v[k] = d2;
                if (d2 < EXT2) act |= (1u << k);   // sqrt deferred to phase 2
            }

            #pragma unroll
            for (int k = 0; k < KPTS; ++k) {
                const unsigned long long mask = __ballot((act >> k) & 1u);
                if (lane == 0) s_wavecnt[k][wv] = __popcll(mask);
            }
            __syncthreads();

            if (tid < KPTS) {
                int o0 = 0;
                #pragma unroll
                for (int w2 = 0; w2 < 4; ++w2) {
                    s_woff[tid][w2] = o0;
                    o0 += s_wavecnt[tid][w2];
                }
                s_base[tid] = (o0 > 0) ? atomicAdd(&cnt[tid * CNT_STRIDE], o0) : 0;
            }
            __syncthreads();

            const unsigned long long lt = (lane == 63) ? 0x7fffffffffffffffull
                                                       : ((1ull << lane) - 1ull);
            const unsigned sd = ((unsigned)s << 16) | (unsigned)d;
            #pragma unroll
            for (int k = 0; k < KPTS; ++k) {
                const bool a = (act >> k) & 1u;
                const unsigned long long mask = __ballot(a);
                if (a) {
                    const int rank = __popcll(mask & lt);
                    const int idx  = s_base[k] + s_woff[k][wv] + rank;
                    if (idx < CAP)
                        lists[(size_t)k * CAP + idx] =
                            make_uint2(sd, __float_as_uint(d2v[k]));
                }
            }
            __syncthreads();   // protect s_wavecnt WAR before next tile
        }
    }
    grid.sync();

    // ---- phase 2: per-pair matmul, prefix-balanced over all k ----------
    {
        int pref[KPTS + 1];
        pref[0] = 0;
        #pragma unroll
        for (int k = 0; k < KPTS; ++k) {
            int c = cnt[k * CNT_STRIDE];
            if (c > CAP) c = CAP;
            pref[k + 1] = pref[k] + c;
        }
        const int P  = pref[KPTS];
        const int NW = nb * 4;
        const int gw = blockIdx.x * 4 + wv;
        const int start = (int)(((long long)P * gw) / NW);
        const int end   = (int)(((long long)P * (gw + 1)) / NW);

        #pragma unroll
        for (int k = 0; k < KPTS; ++k) {
            const int lo = (start > pref[k]) ? start : pref[k];
            const int hi = (end < pref[k + 1]) ? end : pref[k + 1];
            if (lo < hi) {
                float w[IN_DIM];
                #pragma unroll
                for (int i = 0; i < IN_DIM; ++i)
                    w[i] = W[k * (IN_DIM * OUT_DIM) + i * OUT_DIM + lane];

                const uint2* __restrict__ lk = lists + (size_t)k * CAP;
                const int off = pref[k];

                for (int p = lo; p < hi; p += 2) {
                    if (p + 1 < hi) {
                        const uint2 e0 = lk[p - off];
                        const uint2 e1 = lk[p + 1 - off];
                        const unsigned sd0 = (unsigned)__builtin_amdgcn_readfirstlane((int)e0.x);
                        const unsigned sd1 = (unsigned)__builtin_amdgcn_readfirstlane((int)e1.x);
                        const float m0 = 1.0f - sqrtf(fmaxf(__uint_as_float(e0.y), 0.0f)) * INV_EXT;
                        const float m1 = 1.0f - sqrtf(fmaxf(__uint_as_float(e1.y), 0.0f)) * INV_EXT;

                        const float* __restrict__ f0 = feat + ((sd0 >> 16) << 5);
                        const float* __restrict__ f1 = feat + ((sd1 >> 16) << 5);

                        float a0 = 0.0f, b0 = 0.0f, a1 = 0.0f, b1 = 0.0f;
                        #pragma unroll
                        for (int i = 0; i < 16; ++i) {
                            a0 = fmaf(f0[i],      w[i],      a0);
                            b0 = fmaf(f0[i + 16], w[i + 16], b0);
                            a1 = fmaf(f1[i],      w[i],      a1);
                            b1 = fmaf(f1[i + 16], w[i + 16], b1);
                        }
                        const float r0 = m0 * (a0 + b0);
                        const float r1 = m1 * (a1 + b1);
                        const int d0 = (int)(sd0 & 0xffffu);
                        const int d1 = (int)(sd1 & 0xffffu);

                        int t = 0;
                        if (lane == 0) t = atomicAdd(pcnt + d0, 1);
                        if (lane == 1) t = atomicAdd(pcnt + d1, 1);
                        const int s0 = __shfl(t, 0);
                        const int s1 = __shfl(t, 1);

                        if (s0 < scap) slots[((size_t)d0 * scap + s0) * OUT_DIM + lane] = r0;
                        else           atomicAdd(out + (size_t)d0 * OUT_DIM + lane, r0);
                        if (s1 < scap) slots[((size_t)d1 * scap + s1) * OUT_DIM + lane] = r1;
                        else           atomicAdd(out + (size_t)d1 * OUT_DIM + lane, r1);
                    } else {
                        const uint2 e0 = lk[p - off];
                        const unsigned sd = (unsigned)__builtin_amdgcn_readfirstlane((int)e0.x);
                        const float m = 1.0f - sqrtf(fmaxf(__uint_as_float(e0.y), 0.0f)) * INV_EXT;
                        const float* __restrict__ f = feat + ((sd >> 16) << 5);

                        float a = 0.0f, b = 0.0f;
                        #pragma unroll
                        for (int i = 0; i < 16; ++i) {
                            a = fmaf(f[i],      w[i],      a);
                            b = fmaf(f[i + 16], w[i + 16], b);
                        }
                        const float r = m * (a + b);
                        const int d = (int)(sd & 0xffffu);

                        int t = 0;
                        if (lane == 0) t = atomicAdd(pcnt + d, 1);
                        const int s0 = __shfl(t, 0);

                        if (s0 < scap) slots[((size_t)d * scap + s0) * OUT_DIM + lane] = r;
                        else           atomicAdd(out + (size_t)d * OUT_DIM + lane, r);
                    }
                }
            }
        }
    }
    grid.sync();

    // ---- phase 3: per-node slot reduction ------------------------------
    for (int node = blockIdx.x * 4 + wv; node < N_NODES; node += nb * 4) {
        const int raw = pcnt[node];
        int deg = raw;
        if (deg > scap) deg = scap;

        const float* __restrict__ sp = slots + ((size_t)node * scap) * OUT_DIM + lane;

        float a0 = (raw > scap) ? out[(size_t)node * OUT_DIM + lane] : 0.0f;
        float a1 = 0.0f;
        int j = 0;
        for (; j + 1 < deg; j += 2) {
            a0 += sp[(size_t)j * OUT_DIM];
            a1 += sp[(size_t)(j + 1) * OUT_DIM];
        }
        if (j < deg) a1 += sp[(size_t)j * OUT_DIM];

        out[(size_t)node * OUT_DIM + lane] = a0 + a1;
    }
}

// ===========================================================================
// Fallback path (non-cooperative): proven round-3 structure, d2 list format.
// ===========================================================================
__global__ __launch_bounds__(256) void geom_compact(
    const float* __restrict__ pos,
    const float* __restrict__ kp,
    const int*   __restrict__ esrc,
    const int*   __restrict__ edst,
    int*         __restrict__ cnt,
    uint2*       __restrict__ lists,
    float4*      __restrict__ outz)
{
    __shared__ int s_wavecnt[KPTS][4];
    __shared__ int s_woff[KPTS][4];
    __shared__ int s_base[KPTS];

    const int tid  = threadIdx.x;
    const int wv   = tid >> 6;
    const int lane = tid & 63;

    const int e = blockIdx.x * 256 + tid;
    outz[e] = make_float4(0.0f, 0.0f, 0.0f, 0.0f);

    const int s = esrc[e];
    const int d = edst[e];

    const float yx = pos[s * 3 + 0] - pos[d * 3 + 0];
    const float yy = pos[s * 3 + 1] - pos[d * 3 + 1];
    const float yz = pos[s * 3 + 2] - pos[d * 3 + 2];

    float d2v[KPTS];
    unsigned act = 0;
    #pragma unroll
    for (int k = 0; k < KPTS; ++k) {
        const float dx = yx - kp[k * 3 + 0];
        const float dy = yy - kp[k * 3 + 1];
        const float dz = yz - kp[k * 3 + 2];
        const float d2 = dx * dx + dy * dy + dz * dz;
        d2v[k] = d2;
        if (d2 < EXT2) act |= (1u << k);
    }

    #pragma unroll
    for (int k = 0; k < KPTS; ++k) {
        const unsigned long long mask = __ballot((act >> k) & 1u);
        if (lane == 0) s_wavecnt[k][wv] = __popcll(mask);
    }
    __syncthreads();

    if (tid < KPTS) {
        int o0 = 0;
        #pragma unroll
        for (int w = 0; w < 4; ++w) {
            s_woff[tid][w] = o0;
            o0 += s_wavecnt[tid][w];
        }
        s_base[tid] = (o0 > 0) ? atomicAdd(&cnt[tid * CNT_STRIDE], o0) : 0;
    }
    __syncthreads();

    const unsigned long long lt = (lane == 63) ? 0x7fffffffffffffffull
                                               : ((1ull << lane) - 1ull);
    const unsigned sd = ((unsigned)s << 16) | (unsigned)d;
    #pragma unroll
    for (int k = 0; k < KPTS; ++k) {
        const bool a = (act >> k) & 1u;
        const unsigned long long mask = __ballot(a);
        if (a) {
            const int rank = __popcll(mask & lt);
            const int idx  = s_base[k] + s_woff[k][wv] + rank;
            if (idx < CAP)
                lists[(size_t)k * CAP + idx] = make_uint2(sd, __float_as_uint(d2v[k]));
        }
    }
}

#define BPK 256
__global__ __launch_bounds__(256) void pair_matmul(
    const float* __restrict__ feat,
    const float* __restrict__ W,
    const int*   __restrict__ cnt,
    const uint2* __restrict__ lists,
    float*       __restrict__ out,
    int*         __restrict__ pcnt,
    float*       __restrict__ slots,
    const int scap)
{
    const int k    = blockIdx.x % KPTS;
    const int bk   = blockIdx.x / KPTS;
    const int wv   = threadIdx.x >> 6;
    const int lane = threadIdx.x & 63;

    float w[IN_DIM];
    #pragma unroll
    for (int i = 0; i < IN_DIM; ++i)
        w[i] = W[k * (IN_DIM * OUT_DIM) + i * OUT_DIM + lane];

    int n = cnt[k * CNT_STRIDE];
    if (n > CAP) n = CAP;
    const uint2* __restrict__ list = lists + (size_t)k * CAP;

    const int widx    = bk * 4 + wv;
    const int stride2 = BPK * 4 * 2;

    for (int base = widx * 2; base < n; base += stride2) {
        const int lim = (base + 2 < n) ? base + 2 : n;
        for (int p = base; p < lim; ++p) {
            const uint2 ent = list[p];
            const unsigned sd = (unsigned)__builtin_amdgcn_readfirstlane((int)ent.x);
            const float m = 1.0f - sqrtf(fmaxf(__uint_as_float(ent.y), 0.0f)) * INV_EXT;
            const float* __restrict__ f = feat + ((sd >> 16) << 5);

            float a = 0.0f, b = 0.0f;
            #pragma unroll
            for (int i = 0; i < 16; ++i) {
                a = fmaf(f[i],      w[i],      a);
                b = fmaf(f[i + 16], w[i + 16], b);
            }
            const float r = m * (a + b);
            const int d = (int)(sd & 0xffffu);

            int t = 0;
            if (lane == 0) t = atomicAdd(pcnt + d, 1);
            const int s0 = __shfl(t, 0);

            if (s0 < scap) slots[((size_t)d * scap + s0) * OUT_DIM + lane] = r;
            else           atomicAdd(out + (size_t)d * OUT_DIM + lane, r);
        }
    }
}

__global__ __launch_bounds__(256) void node_reduce(
    const int*   __restrict__ pcnt,
    const float* __restrict__ slots,
    float*       __restrict__ out,
    const int scap)
{
    const int wv   = threadIdx.x >> 6;
    const int lane = threadIdx.x & 63;
    const int node = blockIdx.x * 4 + wv;

    const int raw = pcnt[node];
    int deg = raw;
    if (deg > scap) deg = scap;

    const float* __restrict__ sp = slots + ((size_t)node * scap) * OUT_DIM + lane;

    float a0 = (raw > scap) ? out[(size_t)node * OUT_DIM + lane] : 0.0f;
    float a1 = 0.0f;
    int j = 0;
    for (; j + 1 < deg; j += 2) {
        a0 += sp[(size_t)j * OUT_DIM];
        a1 += sp[(size_t)(j + 1) * OUT_DIM];
    }
    if (j < deg) a1 += sp[(size_t)j * OUT_DIM];

    out[(size_t)node * OUT_DIM + lane] = a0 + a1;
}

// ===========================================================================
extern "C" void kernel_launch(void* const* d_in, const int* in_sizes, int n_in,
                              void* d_out, int out_size, void* d_ws, size_t ws_size,
                              hipStream_t stream)
{
    const float* pos  = (const float*)d_in[0];   // [50000,3]
    const float* feat = (const float*)d_in[1];   // [50000,32]
    const float* kp   = (const float*)d_in[2];   // [15,3]
    const float* W    = (const float*)d_in[3];   // [15,32,64]
    const int* esrc   = (const int*)d_in[4];     // [800000]
    const int* edst   = (const int*)d_in[5];     // [800000]
    float* out        = (float*)d_out;           // [50000,64]

    int*   cnt   = (int*)d_ws;
    int*   pcnt  = (int*)((char*)d_ws + PCNT_OFF);
    uint2* lists = (uint2*)((char*)d_ws + LIST_OFF);
    float* slots = (float*)((char*)d_ws + SLOT_OFF);

    const size_t layer_bytes = (size_t)N_NODES * OUT_DIM * sizeof(float); // 12.8MB
    int scap = 0;
    if (ws_size >= (size_t)SLOT_OFF + layer_bytes) {
        scap = (int)((ws_size - (size_t)SLOT_OFF) / layer_bytes);
        if (scap > SCAP_MAX) scap = SCAP_MAX;
    }

    static int coop_ok = -1;
    if (coop_ok < 0) {
        int v = 0;
        if (hipDeviceGetAttribute(&v, hipDeviceAttributeCooperativeLaunch, 0)
            != hipSuccess) v = 0;
        coop_ok = v;
    }

    if (coop_ok) {
        void* args[] = {
            (void*)&pos, (void*)&feat, (void*)&kp, (void*)&W,
            (void*)&esrc, (void*)&edst,
            (void*)&cnt, (void*)&pcnt, (void*)&lists, (void*)&slots,
            (void*)&out, (void*)&scap
        };
        hipError_t err = hipLaunchCooperativeKernel(
            (const void*)kpconv_fused, dim3(GRID_BLOCKS), dim3(256),
            args, 0, stream);
        if (err == hipSuccess) return;
        (void)hipGetLastError();   // clear; fall through to classic path
    }

    // ---- fallback: classic 4-dispatch path -----------------------------
    hipMemsetAsync(d_ws, 0, LIST_OFF, stream);   // counters + pcnt
    geom_compact<<<EDGE_TILES, 256, 0, stream>>>(pos, kp, esrc, edst, cnt, lists,
                                                 (float4*)out);
    pair_matmul<<<BPK * KPTS, 256, 0, stream>>>(feat, W, cnt, lists, out,
                                                pcnt, slots, scap);
    if (scap > 0)
        node_reduce<<<N_NODES / 4, 256, 0, stream>>>(pcnt, slots, out, scap);
}

// Round 5
// 140.039 us; speedup vs baseline: 4.0073x; 4.0073x over previous
//
#include <hip/hip_runtime.h>
#include <hip/hip_bf16.h>

#define N_NODES 50000
#define N_EDGES 800000
#define KPTS 15
#define IN_DIM 32
#define OUT_DIM 64
#define KP_EXTENT 0.6f
#define INV_EXT (1.0f / KP_EXTENT)
#define EXT2 (KP_EXTENT * KP_EXTENT)

#define CAP 131072            // per-k total list capacity
#define NREP 16               // counter/list replicas per k (atomic de-serialization)
#define SEG_CAP (CAP / NREP)  // 8192 entries per (k,replica) segment (~10x margin)
#define CNT_STRIDE 32         // ints: 128B between counters -> distinct cachelines
#define K1_BLOCKS (N_EDGES / 256)   // 3125
#define SUBB 16               // blocks per segment in K2 -> 240*16 = 3840 blocks

// ws layout:
//   [0,      32768)  240 replica counters (stride 128B)
//   [32768, 232768)  pcnt[50000] slot counters
//   [262144, ~16MB)  15 lists of CAP uint2 (sd, d2-bits), each split in 16 segs
//   [16MB,  ...   )  slots[50000][scap][64] fp32 partial rows
#define PCNT_OFF 32768
#define LIST_OFF 262144
#define SLOT_OFF 16777216
#define SCAP_MAX 8

// ---------------------------------------------------------------------------
// K1: geometry (1 lane = 1 edge) + ballot compaction into per-(k,replica)
// segments. Replica = blockIdx&15 -> per-address atomic RMWs drop 3125->~195.
// Also zeroes `out` (800000 float4 == 50000*64 floats exactly).
// ---------------------------------------------------------------------------
__global__ __launch_bounds__(256) void geom_compact(
    const float* __restrict__ pos,
    const float* __restrict__ kp,
    const int*   __restrict__ esrc,
    const int*   __restrict__ edst,
    int*         __restrict__ cnt,     // 240 padded counters
    uint2*       __restrict__ lists,   // 15 * CAP entries (16 segs per k)
    float4*      __restrict__ outz)    // out viewed as float4[800000]
{
    __shared__ int s_wavecnt[KPTS][4];
    __shared__ int s_woff[KPTS][4];
    __shared__ int s_base[KPTS];

    const int tid  = threadIdx.x;
    const int wv   = tid >> 6;
    const int lane = tid & 63;
    const int rep  = blockIdx.x & (NREP - 1);

    const int e = blockIdx.x * 256 + tid;      // grid covers E exactly

    // zero the output (fire-and-forget store)
    outz[e] = make_float4(0.0f, 0.0f, 0.0f, 0.0f);

    const int s = esrc[e];
    const int d = edst[e];

    const float yx = pos[s * 3 + 0] - pos[d * 3 + 0];
    const float yy = pos[s * 3 + 1] - pos[d * 3 + 1];
    const float yz = pos[s * 3 + 2] - pos[d * 3 + 2];

    float d2v[KPTS];
    unsigned act = 0;
    #pragma unroll
    for (int k = 0; k < KPTS; ++k) {
        const float dx = yx - kp[k * 3 + 0];
        const float dy = yy - kp[k * 3 + 1];
        const float dz = yz - kp[k * 3 + 2];
        const float d2 = dx * dx + dy * dy + dz * dz;
        d2v[k] = d2;
        if (d2 < EXT2) act |= (1u << k);   // sqrt deferred to K2
    }

    // per-wave popcounts
    #pragma unroll
    for (int k = 0; k < KPTS; ++k) {
        const unsigned long long mask = __ballot((act >> k) & 1u);
        if (lane == 0) s_wavecnt[k][wv] = __popcll(mask);
    }
    __syncthreads();

    if (tid < KPTS) {
        int o0 = 0;
        #pragma unroll
        for (int w = 0; w < 4; ++w) {
            s_woff[tid][w] = o0;
            o0 += s_wavecnt[tid][w];
        }
        s_base[tid] = (o0 > 0)
            ? atomicAdd(&cnt[(tid * NREP + rep) * CNT_STRIDE], o0) : 0;
    }
    __syncthreads();

    const unsigned long long lt = (lane == 63) ? 0x7fffffffffffffffull
                                               : ((1ull << lane) - 1ull);
    const unsigned sd = ((unsigned)s << 16) | (unsigned)d;
    #pragma unroll
    for (int k = 0; k < KPTS; ++k) {
        const bool a = (act >> k) & 1u;
        const unsigned long long mask = __ballot(a);
        if (a) {
            const int rank = __popcll(mask & lt);
            const int idx  = s_base[k] + s_woff[k][wv] + rank;
            if (idx < SEG_CAP)
                lists[(size_t)k * CAP + (size_t)rep * SEG_CAP + idx] =
                    make_uint2(sd, __float_as_uint(d2v[k]));
        }
    }
}

// ---------------------------------------------------------------------------
// K2: one wave per 2-pair chunk of a (k,replica) segment; lane = out channel.
// W[k] column FORCED into 32 VGPRs (asm keep-alive defeats load sinking).
// Output: one scalar int atomic allocates a slot; plain coalesced 256B store.
// ---------------------------------------------------------------------------
__global__ __launch_bounds__(256) void pair_matmul(
    const float* __restrict__ feat,
    const float* __restrict__ W,       // [15][32][64]
    const int*   __restrict__ cnt,
    const uint2* __restrict__ lists,
    float*       __restrict__ out,
    int*         __restrict__ pcnt,
    float*       __restrict__ slots,
    const int scap)
{
    const int seg  = blockIdx.x % (KPTS * NREP);   // 0..239
    const int sub  = blockIdx.x / (KPTS * NREP);   // 0..SUBB-1
    const int k    = seg >> 4;
    const int rep  = seg & (NREP - 1);
    const int wv   = threadIdx.x >> 6;
    const int lane = threadIdx.x & 63;

    // preload W[k][i][lane] -> 32 VGPRs; keep-alive forces materialization
    float w[IN_DIM];
    #pragma unroll
    for (int i = 0; i < IN_DIM; ++i)
        w[i] = W[k * (IN_DIM * OUT_DIM) + i * OUT_DIM + lane];
    #pragma unroll
    for (int i = 0; i < IN_DIM; ++i)
        asm volatile("" : "+v"(w[i]));

    int n = cnt[seg * CNT_STRIDE];
    if (n > SEG_CAP) n = SEG_CAP;
    const uint2* __restrict__ list =
        lists + (size_t)k * CAP + (size_t)rep * SEG_CAP;

    const int widx    = sub * 4 + wv;              // 0..63
    const int stride2 = SUBB * 4 * 2;              // 128

    for (int base = widx * 2; base < n; base += stride2) {
        if (base + 1 < n) {
            // 16B-aligned (base even), broadcast across the wave
            const uint4 ee = *reinterpret_cast<const uint4*>(list + base);
            const unsigned sd0 = (unsigned)__builtin_amdgcn_readfirstlane((int)ee.x);
            const unsigned sd1 = (unsigned)__builtin_amdgcn_readfirstlane((int)ee.z);
            const float m0 = 1.0f - sqrtf(fmaxf(__uint_as_float(ee.y), 0.0f)) * INV_EXT;
            const float m1 = 1.0f - sqrtf(fmaxf(__uint_as_float(ee.w), 0.0f)) * INV_EXT;

            const float* __restrict__ f0 = feat + ((sd0 >> 16) << 5);  // s_load
            const float* __restrict__ f1 = feat + ((sd1 >> 16) << 5);

            float a0 = 0.0f, b0 = 0.0f, a1 = 0.0f, b1 = 0.0f;
            #pragma unroll
            for (int i = 0; i < 16; ++i) {
                a0 = fmaf(f0[i],      w[i],      a0);
                b0 = fmaf(f0[i + 16], w[i + 16], b0);
                a1 = fmaf(f1[i],      w[i],      a1);
                b1 = fmaf(f1[i + 16], w[i + 16], b1);
            }
            const float r0 = m0 * (a0 + b0);
            const float r1 = m1 * (a1 + b1);
            const int d0 = (int)(sd0 & 0xffffu);
            const int d1 = (int)(sd1 & 0xffffu);

            int t = 0;
            if (lane == 0) t = atomicAdd(pcnt + d0, 1);
            if (lane == 1) t = atomicAdd(pcnt + d1, 1);
            const int s0 = __shfl(t, 0);
            const int s1 = __shfl(t, 1);

            if (s0 < scap) slots[((size_t)d0 * scap + s0) * OUT_DIM + lane] = r0;
            else           atomicAdd(out + (size_t)d0 * OUT_DIM + lane, r0);
            if (s1 < scap) slots[((size_t)d1 * scap + s1) * OUT_DIM + lane] = r1;
            else           atomicAdd(out + (size_t)d1 * OUT_DIM + lane, r1);
        } else {
            const uint2 ent = list[base];
            const unsigned sd = (unsigned)__builtin_amdgcn_readfirstlane((int)ent.x);
            const float m = 1.0f - sqrtf(fmaxf(__uint_as_float(ent.y), 0.0f)) * INV_EXT;
            const float* __restrict__ f = feat + ((sd >> 16) << 5);

            float a = 0.0f, b = 0.0f;
            #pragma unroll
            for (int i = 0; i < 16; ++i) {
                a = fmaf(f[i],      w[i],      a);
                b = fmaf(f[i + 16], w[i + 16], b);
            }
            const float r = m * (a + b);
            const int d = (int)(sd & 0xffffu);

            int t = 0;
            if (lane == 0) t = atomicAdd(pcnt + d, 1);
            const int s0 = __shfl(t, 0);

            if (s0 < scap) slots[((size_t)d * scap + s0) * OUT_DIM + lane] = r;
            else           atomicAdd(out + (size_t)d * OUT_DIM + lane, r);
        }
    }
}

// ---------------------------------------------------------------------------
// K3: one wave per node (4 nodes/block, 12500 blocks); sum slot rows
// (coalesced 256B loads) + write out.
// ---------------------------------------------------------------------------
__global__ __launch_bounds__(256) void node_reduce(
    const int*   __restrict__ pcnt,
    const float* __restrict__ slots,
    float*       __restrict__ out,
    const int scap)
{
    const int wv   = threadIdx.x >> 6;
    const int lane = threadIdx.x & 63;
    const int node = blockIdx.x * 4 + wv;        // 12500*4 == 50000 exactly

    const int raw = pcnt[node];
    int deg = raw;
    if (deg > scap) deg = scap;

    const float* __restrict__ sp = slots + ((size_t)node * scap) * OUT_DIM + lane;

    // overflow atomics (rare) already landed in out; otherwise row is zero
    float a0 = (raw > scap) ? out[(size_t)node * OUT_DIM + lane] : 0.0f;
    float a1 = 0.0f;

    int j = 0;
    for (; j + 1 < deg; j += 2) {
        a0 += sp[(size_t)j * OUT_DIM];
        a1 += sp[(size_t)(j + 1) * OUT_DIM];
    }
    if (j < deg) a1 += sp[(size_t)j * OUT_DIM];

    out[(size_t)node * OUT_DIM + lane] = a0 + a1;
}

// ---------------------------------------------------------------------------
extern "C" void kernel_launch(void* const* d_in, const int* in_sizes, int n_in,
                              void* d_out, int out_size, void* d_ws, size_t ws_size,
                              hipStream_t stream)
{
    const float* pos  = (const float*)d_in[0];   // [50000,3]
    const float* feat = (const float*)d_in[1];   // [50000,32]
    const float* kp   = (const float*)d_in[2];   // [15,3]
    const float* W    = (const float*)d_in[3];   // [15,32,64]
    const int* esrc   = (const int*)d_in[4];     // [800000]
    const int* edst   = (const int*)d_in[5];     // [800000]
    float* out        = (float*)d_out;           // [50000,64]

    int*   cnt   = (int*)d_ws;
    int*   pcnt  = (int*)((char*)d_ws + PCNT_OFF);
    uint2* lists = (uint2*)((char*)d_ws + LIST_OFF);
    float* slots = (float*)((char*)d_ws + SLOT_OFF);

    // slot capacity from available workspace (graceful fallback to atomics)
    const size_t layer_bytes = (size_t)N_NODES * OUT_DIM * sizeof(float); // 12.8MB
    int scap = 0;
    if (ws_size >= (size_t)SLOT_OFF + layer_bytes) {
        scap = (int)((ws_size - (size_t)SLOT_OFF) / layer_bytes);
        if (scap > SCAP_MAX) scap = SCAP_MAX;
    }

    hipMemsetAsync(d_ws, 0, LIST_OFF, stream);   // counters + pcnt (256KB)

    geom_compact<<<K1_BLOCKS, 256, 0, stream>>>(pos, kp, esrc, edst, cnt, lists,
                                                (float4*)out);
    pair_matmul<<<SUBB * KPTS * NREP, 256, 0, stream>>>(feat, W, cnt, lists, out,
                                                        pcnt, slots, scap);
    if (scap > 0)
        node_reduce<<<N_NODES / 4, 256, 0, stream>>>(pcnt, slots, out, scap);
}

// Round 6
// 134.225 us; speedup vs baseline: 4.1808x; 1.0433x over previous
//
#include <hip/hip_runtime.h>
#include <hip/hip_fp16.h>

#define N_NODES 50000
#define N_EDGES 800000
#define KPTS 15
#define IN_DIM 32
#define OUT_DIM 64
#define KP_EXTENT 0.6f
#define INV_EXT (1.0f / KP_EXTENT)
#define EXT2 (KP_EXTENT * KP_EXTENT)

#define CAP 131072            // per-k total list capacity
#define NREP 16               // counter/list replicas per k (atomic de-serialization)
#define SEG_CAP (CAP / NREP)  // 8192 entries per (k,replica) segment
#define CNT_STRIDE 32         // ints: 128B between counters -> distinct cachelines
#define K1_BLOCKS (N_EDGES / 256)   // 3125
#define SUBB 16               // blocks per segment in K2 -> 240*16 = 3840 blocks

// ws layout:
//   [0,      32768)  240 replica counters (stride 128B)
//   [32768, 232768)  pcnt[50000] slot counters
//   [262144, ~16MB)  15 lists of CAP uint2, each split in 16 segments
//                    entry: x = (src<<16) | fp16(m), y = slot byte/4 offset
//                           or 0x80000000|d on overflow
//   [16MB,  ...   )  slots[50000][scap][64] fp32 partial rows
#define PCNT_OFF 32768
#define LIST_OFF 262144
#define SLOT_OFF 16777216
#define SCAP_MAX 8

// ---------------------------------------------------------------------------
// K1: geometry (1 lane = 1 edge) + ballot compaction into per-(k,replica)
// segments. NEW: allocates the destination slot here (atomicAdd(pcnt) hidden
// by 800k-thread TLP) and stores the precomputed slot offset + fp16 m in the
// entry, so K2 has zero bookkeeping. Also zeroes `out`.
// ---------------------------------------------------------------------------
__global__ __launch_bounds__(256) void geom_compact(
    const float* __restrict__ pos,
    const float* __restrict__ kp,
    const int*   __restrict__ esrc,
    const int*   __restrict__ edst,
    int*         __restrict__ cnt,     // 240 padded counters
    int*         __restrict__ pcnt,    // per-node slot counters
    uint2*       __restrict__ lists,   // 15 * CAP entries (16 segs per k)
    float4*      __restrict__ outz,    // out viewed as float4[800000]
    const int scap)
{
    __shared__ int s_wavecnt[KPTS][4];
    __shared__ int s_woff[KPTS][4];
    __shared__ int s_base[KPTS];

    const int tid  = threadIdx.x;
    const int wv   = tid >> 6;
    const int lane = tid & 63;
    const int rep  = blockIdx.x & (NREP - 1);

    const int e = blockIdx.x * 256 + tid;      // grid covers E exactly

    // zero the output (fire-and-forget store)
    outz[e] = make_float4(0.0f, 0.0f, 0.0f, 0.0f);

    const int s = esrc[e];
    const int d = edst[e];

    const float yx = pos[s * 3 + 0] - pos[d * 3 + 0];
    const float yy = pos[s * 3 + 1] - pos[d * 3 + 1];
    const float yz = pos[s * 3 + 2] - pos[d * 3 + 2];

    float d2v[KPTS];
    unsigned act = 0;
    #pragma unroll
    for (int k = 0; k < KPTS; ++k) {
        const float dx = yx - kp[k * 3 + 0];
        const float dy = yy - kp[k * 3 + 1];
        const float dz = yz - kp[k * 3 + 2];
        const float d2 = dx * dx + dy * dy + dz * dz;
        d2v[k] = d2;
        if (d2 < EXT2) act |= (1u << k);
    }

    // per-wave popcounts
    #pragma unroll
    for (int k = 0; k < KPTS; ++k) {
        const unsigned long long mask = __ballot((act >> k) & 1u);
        if (lane == 0) s_wavecnt[k][wv] = __popcll(mask);
    }
    __syncthreads();

    if (tid < KPTS) {
        int o0 = 0;
        #pragma unroll
        for (int w = 0; w < 4; ++w) {
            s_woff[tid][w] = o0;
            o0 += s_wavecnt[tid][w];
        }
        s_base[tid] = (o0 > 0)
            ? atomicAdd(&cnt[(tid * NREP + rep) * CNT_STRIDE], o0) : 0;
    }
    __syncthreads();

    const unsigned long long lt = (lane == 63) ? 0x7fffffffffffffffull
                                               : ((1ull << lane) - 1ull);
    #pragma unroll
    for (int k = 0; k < KPTS; ++k) {
        const bool a = (act >> k) & 1u;
        const unsigned long long mask = __ballot(a);
        if (a) {
            const int rank = __popcll(mask & lt);
            const int idx  = s_base[k] + s_woff[k][wv] + rank;
            if (idx < SEG_CAP) {
                // m as fp16, packed with src
                const float mk = 1.0f - sqrtf(d2v[k]) * INV_EXT;
                __half hm = __float2half(mk);
                const unsigned mh = *reinterpret_cast<unsigned short*>(&hm);

                // slot allocation (latency hidden by massive TLP here)
                const int t = atomicAdd(pcnt + d, 1);
                const unsigned ey = (t < scap)
                    ? (unsigned)((d * scap + t) * OUT_DIM)    // < 2^25, bit31 clear
                    : (0x80000000u | (unsigned)d);            // overflow sentinel

                lists[(size_t)k * CAP + (size_t)rep * SEG_CAP + idx] =
                    make_uint2(((unsigned)s << 16) | mh, ey);
            }
        }
    }
}

// ---------------------------------------------------------------------------
// K2: one wave per 2-pair chunk of a (k,replica) segment; lane = out channel.
// W[k] column forced into 32 VGPRs. Pure load -> dot -> plain 256B store at
// the precomputed slot offset (no atomics, no shuffles). Next-chunk entries
// prefetched so vmem latency hides under the FMA chain.
// ---------------------------------------------------------------------------
__global__ __launch_bounds__(256) void pair_matmul(
    const float* __restrict__ feat,
    const float* __restrict__ W,       // [15][32][64]
    const int*   __restrict__ cnt,
    const uint2* __restrict__ lists,
    float*       __restrict__ out,
    float*       __restrict__ slots)
{
    const int seg  = blockIdx.x % (KPTS * NREP);   // 0..239
    const int sub  = blockIdx.x / (KPTS * NREP);   // 0..SUBB-1
    const int k    = seg >> 4;
    const int rep  = seg & (NREP - 1);
    const int wv   = threadIdx.x >> 6;
    const int lane = threadIdx.x & 63;

    // preload W[k][i][lane] -> 32 VGPRs; keep-alive forces materialization
    float w[IN_DIM];
    #pragma unroll
    for (int i = 0; i < IN_DIM; ++i)
        w[i] = W[k * (IN_DIM * OUT_DIM) + i * OUT_DIM + lane];
    #pragma unroll
    for (int i = 0; i < IN_DIM; ++i)
        asm volatile("" : "+v"(w[i]));

    int n = cnt[seg * CNT_STRIDE];
    if (n > SEG_CAP) n = SEG_CAP;
    const uint2* __restrict__ list =
        lists + (size_t)k * CAP + (size_t)rep * SEG_CAP;

    const int widx    = sub * 4 + wv;              // 0..63
    const int stride2 = SUBB * 4 * 2;              // 128

    int base = widx * 2;
    if (base >= n) return;

    // first chunk (uint4 read may touch entry n within the allocated segment
    // region when base+1==n; value unused)
    uint4 ee = *reinterpret_cast<const uint4*>(list + base);

    for (; base < n; base += stride2) {
        // prefetch next chunk (clamped address keeps the load unconditional)
        const int nb = base + stride2;
        const uint4 en = *reinterpret_cast<const uint4*>(list + (nb < n ? nb : 0));

        const unsigned ex0 = (unsigned)__builtin_amdgcn_readfirstlane((int)ee.x);
        const unsigned ey0 = (unsigned)__builtin_amdgcn_readfirstlane((int)ee.y);
        const bool two = (base + 1 < n);
        const unsigned ex1 = (unsigned)__builtin_amdgcn_readfirstlane((int)ee.z);
        const unsigned ey1 = (unsigned)__builtin_amdgcn_readfirstlane((int)ee.w);

        __half h0; *reinterpret_cast<unsigned short*>(&h0) = (unsigned short)(ex0 & 0xffffu);
        __half h1; *reinterpret_cast<unsigned short*>(&h1) = (unsigned short)(ex1 & 0xffffu);
        const float m0 = __half2float(h0);
        const float m1 = __half2float(h1);

        const float* __restrict__ f0 = feat + ((ex0 >> 16) << 5);  // uniform -> s_load
        const float* __restrict__ f1 = feat + ((ex1 >> 16) << 5);

        if (two) {
            float a0 = 0.0f, b0 = 0.0f, a1 = 0.0f, b1 = 0.0f;
            #pragma unroll
            for (int i = 0; i < 16; ++i) {
                a0 = fmaf(f0[i],      w[i],      a0);
                b0 = fmaf(f0[i + 16], w[i + 16], b0);
                a1 = fmaf(f1[i],      w[i],      a1);
                b1 = fmaf(f1[i + 16], w[i + 16], b1);
            }
            const float r0 = m0 * (a0 + b0);
            const float r1 = m1 * (a1 + b1);

            if (!(ey0 & 0x80000000u)) slots[(size_t)ey0 + lane] = r0;
            else atomicAdd(out + (size_t)(ey0 & 0xffffu) * OUT_DIM + lane, r0);
            if (!(ey1 & 0x80000000u)) slots[(size_t)ey1 + lane] = r1;
            else atomicAdd(out + (size_t)(ey1 & 0xffffu) * OUT_DIM + lane, r1);
        } else {
            float a0 = 0.0f, b0 = 0.0f;
            #pragma unroll
            for (int i = 0; i < 16; ++i) {
                a0 = fmaf(f0[i],      w[i],      a0);
                b0 = fmaf(f0[i + 16], w[i + 16], b0);
            }
            const float r0 = m0 * (a0 + b0);
            if (!(ey0 & 0x80000000u)) slots[(size_t)ey0 + lane] = r0;
            else atomicAdd(out + (size_t)(ey0 & 0xffffu) * OUT_DIM + lane, r0);
        }

        ee = en;
    }
}

// ---------------------------------------------------------------------------
// K3: one wave per node (4 nodes/block, 12500 blocks); sum slot rows
// (coalesced 256B loads) + write out.
// ---------------------------------------------------------------------------
__global__ __launch_bounds__(256) void node_reduce(
    const int*   __restrict__ pcnt,
    const float* __restrict__ slots,
    float*       __restrict__ out,
    const int scap)
{
    const int wv   = threadIdx.x >> 6;
    const int lane = threadIdx.x & 63;
    const int node = blockIdx.x * 4 + wv;        // 12500*4 == 50000 exactly

    const int raw = pcnt[node];
    int deg = raw;
    if (deg > scap) deg = scap;

    const float* __restrict__ sp = slots + ((size_t)node * scap) * OUT_DIM + lane;

    // overflow atomics (rare) already landed in out; otherwise row is zero
    float a0 = (raw > scap) ? out[(size_t)node * OUT_DIM + lane] : 0.0f;
    float a1 = 0.0f;

    int j = 0;
    for (; j + 1 < deg; j += 2) {
        a0 += sp[(size_t)j * OUT_DIM];
        a1 += sp[(size_t)(j + 1) * OUT_DIM];
    }
    if (j < deg) a1 += sp[(size_t)j * OUT_DIM];

    out[(size_t)node * OUT_DIM + lane] = a0 + a1;
}

// ---------------------------------------------------------------------------
extern "C" void kernel_launch(void* const* d_in, const int* in_sizes, int n_in,
                              void* d_out, int out_size, void* d_ws, size_t ws_size,
                              hipStream_t stream)
{
    const float* pos  = (const float*)d_in[0];   // [50000,3]
    const float* feat = (const float*)d_in[1];   // [50000,32]
    const float* kp   = (const float*)d_in[2];   // [15,3]
    const float* W    = (const float*)d_in[3];   // [15,32,64]
    const int* esrc   = (const int*)d_in[4];     // [800000]
    const int* edst   = (const int*)d_in[5];     // [800000]
    float* out        = (float*)d_out;           // [50000,64]

    int*   cnt   = (int*)d_ws;
    int*   pcnt  = (int*)((char*)d_ws + PCNT_OFF);
    uint2* lists = (uint2*)((char*)d_ws + LIST_OFF);
    float* slots = (float*)((char*)d_ws + SLOT_OFF);

    // slot capacity from available workspace (graceful fallback to atomics)
    const size_t layer_bytes = (size_t)N_NODES * OUT_DIM * sizeof(float); // 12.8MB
    int scap = 0;
    if (ws_size >= (size_t)SLOT_OFF + layer_bytes) {
        scap = (int)((ws_size - (size_t)SLOT_OFF) / layer_bytes);
        if (scap > SCAP_MAX) scap = SCAP_MAX;
    }

    hipMemsetAsync(d_ws, 0, LIST_OFF, stream);   // counters + pcnt (256KB)

    geom_compact<<<K1_BLOCKS, 256, 0, stream>>>(pos, kp, esrc, edst, cnt, pcnt,
                                                lists, (float4*)out, scap);
    pair_matmul<<<SUBB * KPTS * NREP, 256, 0, stream>>>(feat, W, cnt, lists,
                                                        out, slots);
    if (scap > 0)
        node_reduce<<<N_NODES / 4, 256, 0, stream>>>(pcnt, slots, out, scap);
}

// Round 7
// 134.164 us; speedup vs baseline: 4.1828x; 1.0005x over previous
//
#include <hip/hip_runtime.h>
#include <hip/hip_fp16.h>

#define N_NODES 50000
#define N_EDGES 800000
#define KPTS 15
#define IN_DIM 32
#define OUT_DIM 64
#define KP_EXTENT 0.6f
#define INV_EXT (1.0f / KP_EXTENT)
#define EXT2 (KP_EXTENT * KP_EXTENT)

#define CAP 131072            // per-k total list capacity
#define NREP 16               // counter/list replicas per k
#define SEG_CAP (CAP / NREP)  // 8192 entries per (k,replica) segment
#define CNT_STRIDE 32         // ints: 128B between counters
#define K1_BLOCKS (N_EDGES / 256)   // 3125
#define SUBB 16               // blocks per segment in K2 -> 240*16 = 3840 blocks

// ws layout (ws = 256 MiB measured):
//   [0,      32768)   240 replica counters (stride 128B)
//   [32768, 232768)   pcnt[50000] slot counters
//   [1MB,   1MB+3.2M) featH[50000][32] packed fp16 (uint per 2 channels)
//   [8MB,   23.7MB)   15 lists of CAP uint2 (x=(src<<16)|fp16(m), y=slot off
//                     in fp32-units, or 0x80000000|d overflow sentinel)
//   [32MB,  134.4MB)  slots16[50000][scap][64] fp16 partial rows (packed uint)
#define PCNT_OFF 32768
#define FEATH_OFF (1u << 20)
#define LIST_OFF  (8u << 20)
#define SLOT_OFF  (32u << 20)
#define SCAP_MAX 16

typedef unsigned int uint;

#define RFL(x) ((uint)__builtin_amdgcn_readfirstlane((int)(x)))

static __device__ __forceinline__ float h2f16(uint u) {
    return __half2float(__ushort_as_half((unsigned short)(u & 0xffffu)));
}
static __device__ __forceinline__ uint pack2(float lo, float hi) {
    return (uint)__half_as_ushort(__float2half_rn(lo))
         | ((uint)__half_as_ushort(__float2half_rn(hi)) << 16);
}

#if __has_builtin(__builtin_amdgcn_fdot2)
typedef _Float16 h2v __attribute__((ext_vector_type(2)));
static __device__ __forceinline__ float fdot2u(uint a, uint b, float c) {
    union U { uint u; h2v h; };
    U ua, ub; ua.u = a; ub.u = b;
    return __builtin_amdgcn_fdot2(ua.h, ub.h, c, false);
}
#else
static __device__ __forceinline__ float fdot2u(uint a, uint b, float c) {
    const float al = h2f16(a), ah = h2f16(a >> 16);
    const float bl = h2f16(b), bh = h2f16(b >> 16);
    return fmaf(ah, bh, fmaf(al, bl, c));
}
#endif

// ---------------------------------------------------------------------------
// K1: geometry + ballot compaction into per-(k,replica) segments, slot
// allocation (atomicAdd(pcnt) hidden by 800k-thread TLP), fp16 m in entry.
// Also zeroes `out` AND converts feat -> packed fp16 (1 uint per thread).
// ---------------------------------------------------------------------------
__global__ __launch_bounds__(256) void geom_compact(
    const float* __restrict__ pos,
    const float* __restrict__ feat,
    const float* __restrict__ kp,
    const int*   __restrict__ esrc,
    const int*   __restrict__ edst,
    int*         __restrict__ cnt,
    int*         __restrict__ pcnt,
    uint2*       __restrict__ lists,
    uint*        __restrict__ featH,   // 800000 uints
    float4*      __restrict__ outz,    // out viewed as float4[800000]
    const int scap)
{
    __shared__ int s_wavecnt[KPTS][4];
    __shared__ int s_woff[KPTS][4];
    __shared__ int s_base[KPTS];

    const int tid  = threadIdx.x;
    const int wv   = tid >> 6;
    const int lane = tid & 63;
    const int rep  = blockIdx.x & (NREP - 1);

    const int e = blockIdx.x * 256 + tid;      // grid covers E exactly

    // zero the output + convert 2 feat channels (both fire-and-forget)
    outz[e] = make_float4(0.0f, 0.0f, 0.0f, 0.0f);
    {
        const float2 fv = ((const float2*)feat)[e];   // 800000 = 50000*32/2
        featH[e] = pack2(fv.x, fv.y);
    }

    const int s = esrc[e];
    const int d = edst[e];

    const float yx = pos[s * 3 + 0] - pos[d * 3 + 0];
    const float yy = pos[s * 3 + 1] - pos[d * 3 + 1];
    const float yz = pos[s * 3 + 2] - pos[d * 3 + 2];

    float d2v[KPTS];
    unsigned act = 0;
    #pragma unroll
    for (int k = 0; k < KPTS; ++k) {
        const float dx = yx - kp[k * 3 + 0];
        const float dy = yy - kp[k * 3 + 1];
        const float dz = yz - kp[k * 3 + 2];
        const float d2 = dx * dx + dy * dy + dz * dz;
        d2v[k] = d2;
        if (d2 < EXT2) act |= (1u << k);
    }

    #pragma unroll
    for (int k = 0; k < KPTS; ++k) {
        const unsigned long long mask = __ballot((act >> k) & 1u);
        if (lane == 0) s_wavecnt[k][wv] = __popcll(mask);
    }
    __syncthreads();

    if (tid < KPTS) {
        int o0 = 0;
        #pragma unroll
        for (int w = 0; w < 4; ++w) {
            s_woff[tid][w] = o0;
            o0 += s_wavecnt[tid][w];
        }
        s_base[tid] = (o0 > 0)
            ? atomicAdd(&cnt[(tid * NREP + rep) * CNT_STRIDE], o0) : 0;
    }
    __syncthreads();

    const unsigned long long lt = (lane == 63) ? 0x7fffffffffffffffull
                                               : ((1ull << lane) - 1ull);
    #pragma unroll
    for (int k = 0; k < KPTS; ++k) {
        const bool a = (act >> k) & 1u;
        const unsigned long long mask = __ballot(a);
        if (a) {
            const int rank = __popcll(mask & lt);
            const int idx  = s_base[k] + s_woff[k][wv] + rank;
            if (idx < SEG_CAP) {
                const float mk = 1.0f - sqrtf(d2v[k]) * INV_EXT;
                __half hm = __float2half(mk);
                const unsigned mh = (unsigned)__half_as_ushort(hm);

                const int t = atomicAdd(pcnt + d, 1);
                const unsigned ey = (t < scap)
                    ? (unsigned)((d * scap + t) * OUT_DIM)    // bit31 clear
                    : (0x80000000u | (unsigned)d);            // overflow

                lists[(size_t)k * CAP + (size_t)rep * SEG_CAP + idx] =
                    make_uint2(((unsigned)s << 16) | mh, ey);
            }
        }
    }
}

// ---------------------------------------------------------------------------
// K2: one wave per 2-pair chunk; lane = output channel. fp16 math via
// v_dot2_f32_f16 (fp32 accumulate). 2-deep pipeline: entries prefetched 2
// chunks ahead, feat rows (16 uints each) preloaded 1 chunk ahead so the L2
// gather latency hides under the current chunk's dot chain. fp16 slot stores
// (even lanes store packed channel pairs).
// ---------------------------------------------------------------------------
__global__ __launch_bounds__(256) void pair_matmul(
    const uint*  __restrict__ featH,
    const float* __restrict__ W,       // [15][32][64] fp32
    const int*   __restrict__ cnt,
    const uint2* __restrict__ lists,
    float*       __restrict__ out,
    uint*        __restrict__ slots16)
{
    const int seg  = blockIdx.x % (KPTS * NREP);   // 0..239
    const int sub  = blockIdx.x / (KPTS * NREP);   // 0..SUBB-1
    const int k    = seg >> 4;
    const int rep  = seg & (NREP - 1);
    const int wv   = threadIdx.x >> 6;
    const int lane = threadIdx.x & 63;

    // W[k] column as packed fp16: wpk[j] = (W[k][2j][lane], W[k][2j+1][lane])
    uint wpk[16];
    #pragma unroll
    for (int j = 0; j < 16; ++j) {
        const float wa = W[k * (IN_DIM * OUT_DIM) + (2 * j)     * OUT_DIM + lane];
        const float wb = W[k * (IN_DIM * OUT_DIM) + (2 * j + 1) * OUT_DIM + lane];
        wpk[j] = pack2(wa, wb);
    }
    #pragma unroll
    for (int j = 0; j < 16; ++j)
        asm volatile("" : "+v"(wpk[j]));

    int n = cnt[seg * CNT_STRIDE];
    if (n > SEG_CAP) n = SEG_CAP;
    const uint2* __restrict__ list =
        lists + (size_t)k * CAP + (size_t)rep * SEG_CAP;

    const int widx    = sub * 4 + wv;              // 0..63
    const int stride2 = SUBB * 4 * 2;              // 128

    int base = widx * 2;
    if (base >= n) return;

    // chunk A entries (current) + chunk B entries (in flight)
    uint4 eeA = *reinterpret_cast<const uint4*>(list + base);
    const int bB0 = base + stride2;
    uint4 eeB = *reinterpret_cast<const uint4*>(list + (bB0 < n ? bB0 : 0));

    // decode A + preload feat A
    uint axA0 = RFL(eeA.x), ayA0 = RFL(eeA.y),
         axA1 = RFL(eeA.z), ayA1 = RFL(eeA.w);
    uint sA0 = axA0 >> 16; if (sA0 >= N_NODES) sA0 = 0;
    uint sA1 = axA1 >> 16; if (sA1 >= N_NODES) sA1 = 0;
    uint faA[16], fbA[16];
    {
        const uint* __restrict__ p0 = featH + sA0 * 16;
        const uint* __restrict__ p1 = featH + sA1 * 16;
        #pragma unroll
        for (int j = 0; j < 16; ++j) { faA[j] = p0[j]; fbA[j] = p1[j]; }
    }

    for (; base < n; base += stride2) {
        // prefetch entries 2 chunks ahead
        const int bC = base + 2 * stride2;
        const uint4 eeC = *reinterpret_cast<const uint4*>(list + (bC < n ? bC : 0));

        // decode B + issue feat-B loads (hide under A's dot chain)
        const uint axB0 = RFL(eeB.x), ayB0 = RFL(eeB.y),
                   axB1 = RFL(eeB.z), ayB1 = RFL(eeB.w);
        uint sB0 = axB0 >> 16; if (sB0 >= N_NODES) sB0 = 0;
        uint sB1 = axB1 >> 16; if (sB1 >= N_NODES) sB1 = 0;
        uint faB[16], fbB[16];
        {
            const uint* __restrict__ p0 = featH + sB0 * 16;
            const uint* __restrict__ p1 = featH + sB1 * 16;
            #pragma unroll
            for (int j = 0; j < 16; ++j) { faB[j] = p0[j]; fbB[j] = p1[j]; }
        }

        // compute chunk A: two independent dot2 chains
        float acc0 = 0.0f, acc1 = 0.0f;
        #pragma unroll
        for (int j = 0; j < 16; ++j) {
            acc0 = fdot2u(faA[j], wpk[j], acc0);
            acc1 = fdot2u(fbA[j], wpk[j], acc1);
        }
        const float m0 = h2f16(axA0);
        const float m1 = h2f16(axA1);
        const float r0 = m0 * acc0;
        const float r1 = m1 * acc1;
        const bool  two = (base + 1 < n);

        const float p0 = __shfl_xor(r0, 1);
        const float p1 = __shfl_xor(r1, 1);

        if (!(ayA0 & 0x80000000u)) {
            if (!(lane & 1))
                slots16[(ayA0 >> 1) + (lane >> 1)] = pack2(r0, p0);
        } else {
            atomicAdd(out + (size_t)(ayA0 & 0xffffu) * OUT_DIM + lane, r0);
        }
        if (two) {
            if (!(ayA1 & 0x80000000u)) {
                if (!(lane & 1))
                    slots16[(ayA1 >> 1) + (lane >> 1)] = pack2(r1, p1);
            } else {
                atomicAdd(out + (size_t)(ayA1 & 0xffffu) * OUT_DIM + lane, r1);
            }
        }

        // rotate pipeline B -> A
        axA0 = axB0; ayA0 = ayB0; axA1 = axB1; ayA1 = ayB1;
        #pragma unroll
        for (int j = 0; j < 16; ++j) { faA[j] = faB[j]; fbA[j] = fbB[j]; }
        eeB = eeC;
    }
}

// ---------------------------------------------------------------------------
// K3: one wave per node; lanes 0..31 each own a channel pair. Sum fp16 slot
// rows (fp32 accumulate), add rare overflow atomics already in out, write
// float2. 25 MB read + 12.8 MB write, BW-bound.
// ---------------------------------------------------------------------------
__global__ __launch_bounds__(256) void node_reduce(
    const int*  __restrict__ pcnt,
    const uint* __restrict__ slots16,
    float*      __restrict__ out,
    const int scap)
{
    const int wv   = threadIdx.x >> 6;
    const int lane = threadIdx.x & 63;
    const int node = blockIdx.x * 4 + wv;        // 12500*4 == 50000 exactly

    if (lane >= 32) return;

    const int raw = pcnt[node];
    int deg = raw;
    if (deg > scap) deg = scap;

    const uint* __restrict__ sp =
        slots16 + (size_t)node * ((size_t)scap * 32) + lane;

    float a0 = 0.0f, a1 = 0.0f, b0 = 0.0f, b1 = 0.0f;
    int j = 0;
    for (; j + 1 < deg; j += 2) {
        const uint u0 = sp[(size_t)j * 32];
        const uint u1 = sp[(size_t)(j + 1) * 32];
        a0 += h2f16(u0); a1 += h2f16(u0 >> 16);
        b0 += h2f16(u1); b1 += h2f16(u1 >> 16);
    }
    if (j < deg) {
        const uint u0 = sp[(size_t)j * 32];
        a0 += h2f16(u0); a1 += h2f16(u0 >> 16);
    }

    float o0 = a0 + b0;
    float o1 = a1 + b1;
    if (raw > scap) {   // overflow atomics already landed in (zeroed) out
        const float2 prev = ((const float2*)out)[(size_t)node * 32 + lane];
        o0 += prev.x; o1 += prev.y;
    }
    ((float2*)out)[(size_t)node * 32 + lane] = make_float2(o0, o1);
}

// ---------------------------------------------------------------------------
extern "C" void kernel_launch(void* const* d_in, const int* in_sizes, int n_in,
                              void* d_out, int out_size, void* d_ws, size_t ws_size,
                              hipStream_t stream)
{
    const float* pos  = (const float*)d_in[0];   // [50000,3]
    const float* feat = (const float*)d_in[1];   // [50000,32]
    const float* kp   = (const float*)d_in[2];   // [15,3]
    const float* W    = (const float*)d_in[3];   // [15,32,64]
    const int* esrc   = (const int*)d_in[4];     // [800000]
    const int* edst   = (const int*)d_in[5];     // [800000]
    float* out        = (float*)d_out;           // [50000,64]

    int*   cnt     = (int*)d_ws;
    int*   pcnt    = (int*)((char*)d_ws + PCNT_OFF);
    uint*  featH   = (uint*)((char*)d_ws + FEATH_OFF);
    uint2* lists   = (uint2*)((char*)d_ws + LIST_OFF);
    uint*  slots16 = (uint*)((char*)d_ws + SLOT_OFF);

    // slot capacity from available workspace (fp16 rows: 128B each)
    const size_t layer_bytes = (size_t)N_NODES * OUT_DIM * 2;   // 6.4MB
    int scap = 0;
    if (ws_size >= (size_t)SLOT_OFF + layer_bytes) {
        scap = (int)((ws_size - (size_t)SLOT_OFF) / layer_bytes);
        if (scap > SCAP_MAX) scap = SCAP_MAX;
    }

    hipMemsetAsync(d_ws, 0, 262144, stream);   // counters + pcnt

    geom_compact<<<K1_BLOCKS, 256, 0, stream>>>(pos, feat, kp, esrc, edst,
                                                cnt, pcnt, lists, featH,
                                                (float4*)out, scap);
    pair_matmul<<<SUBB * KPTS * NREP, 256, 0, stream>>>(featH, W, cnt, lists,
                                                        out, slots16);
    if (scap > 0)
        node_reduce<<<N_NODES / 4, 256, 0, stream>>>(pcnt, slots16, out, scap);
}

// Round 8
// 126.557 us; speedup vs baseline: 4.4341x; 1.0601x over previous
//
#include <hip/hip_runtime.h>
#include <hip/hip_fp16.h>

#define N_NODES 50000
#define N_EDGES 800000
#define KPTS 15
#define IN_DIM 32
#define OUT_DIM 64
#define KP_EXTENT 0.6f
#define INV_EXT (1.0f / KP_EXTENT)
#define EXT2 (KP_EXTENT * KP_EXTENT)

#define CAP 131072            // per-k total list capacity
#define NREP 16               // counter/list replicas per k
#define SEG_CAP (CAP / NREP)  // 8192 entries per (k,replica) segment
#define CNT_STRIDE 32         // ints: 128B between counters
#define K1_BLOCKS (N_EDGES / 256)   // 3125
#define SUBB 16               // blocks per segment in K2 -> 240*16 = 3840 blocks

// ws layout (ws = 256 MiB measured):
//   [0,      32768)   240 replica counters (stride 128B)
//   [32768, 232768)   pcnt[50000] slot counters
//   [1MB,   1MB+3.2M) featH[50000][32] packed fp16 (uint per 2 channels)
//   [8MB,   23.7MB)   15 lists of CAP uint2 (x=(src<<16)|fp16(m), y=slot off
//                     in fp32-units, or 0x80000000|d overflow sentinel)
//   [32MB,  134.4MB)  slots16[50000][scap][64] fp16 partial rows (packed uint)
#define PCNT_OFF 32768
#define FEATH_OFF (1u << 20)
#define LIST_OFF  (8u << 20)
#define SLOT_OFF  (32u << 20)
#define SCAP_MAX 16

typedef unsigned int uint;

#define RFL(x) ((uint)__builtin_amdgcn_readfirstlane((int)(x)))

static __device__ __forceinline__ float h2f16(uint u) {
    return __half2float(__ushort_as_half((unsigned short)(u & 0xffffu)));
}
static __device__ __forceinline__ uint pack2(float lo, float hi) {
    return (uint)__half_as_ushort(__float2half_rn(lo))
         | ((uint)__half_as_ushort(__float2half_rn(hi)) << 16);
}

#if __has_builtin(__builtin_amdgcn_fdot2)
typedef _Float16 h2v __attribute__((ext_vector_type(2)));
static __device__ __forceinline__ float fdot2u(uint a, uint b, float c) {
    union U { uint u; h2v h; };
    U ua, ub; ua.u = a; ub.u = b;
    return __builtin_amdgcn_fdot2(ua.h, ub.h, c, false);
}
#else
// pattern clang fuses to v_fma_mix_f32 (f16 inputs, f32 accumulate)
static __device__ __forceinline__ float fdot2u(uint a, uint b, float c) {
    const float al = h2f16(a), ah = h2f16(a >> 16);
    const float bl = h2f16(b), bh = h2f16(b >> 16);
    return fmaf(ah, bh, fmaf(al, bl, c));
}
#endif

// ---------------------------------------------------------------------------
// K1: geometry + ballot compaction into per-(k,replica) segments.
// This round: ballot masks computed once (kept in VGPRs), ONE pcnt atomic per
// active edge (popcount(act) slots, issued early so latency hides under the
// barriers), wave-uniform skip of empty k-iterations in the write phase.
// Also zeroes `out` and converts feat -> packed fp16.
// ---------------------------------------------------------------------------
__global__ __launch_bounds__(256) void geom_compact(
    const float* __restrict__ pos,
    const float* __restrict__ feat,
    const float* __restrict__ kp,
    const int*   __restrict__ esrc,
    const int*   __restrict__ edst,
    int*         __restrict__ cnt,
    int*         __restrict__ pcnt,
    uint2*       __restrict__ lists,
    uint*        __restrict__ featH,   // 800000 uints
    float4*      __restrict__ outz,    // out viewed as float4[800000]
    uint*        __restrict__ slots16, // for rare list-overflow zero-fill
    const int scap)
{
    __shared__ int s_wavecnt[KPTS][4];
    __shared__ int s_woff[KPTS][4];
    __shared__ int s_base[KPTS];

    const int tid  = threadIdx.x;
    const int wv   = tid >> 6;
    const int lane = tid & 63;
    const int rep  = blockIdx.x & (NREP - 1);

    const int e = blockIdx.x * 256 + tid;      // grid covers E exactly

    // zero the output + convert 2 feat channels (fire-and-forget)
    outz[e] = make_float4(0.0f, 0.0f, 0.0f, 0.0f);
    {
        const float2 fv = ((const float2*)feat)[e];   // 800000 = 50000*32/2
        featH[e] = pack2(fv.x, fv.y);
    }

    const int s = esrc[e];
    const int d = edst[e];

    const float yx = pos[s * 3 + 0] - pos[d * 3 + 0];
    const float yy = pos[s * 3 + 1] - pos[d * 3 + 1];
    const float yz = pos[s * 3 + 2] - pos[d * 3 + 2];

    float d2v[KPTS];
    unsigned act = 0;
    #pragma unroll
    for (int k = 0; k < KPTS; ++k) {
        const float dx = yx - kp[k * 3 + 0];
        const float dy = yy - kp[k * 3 + 1];
        const float dz = yz - kp[k * 3 + 2];
        const float d2 = dx * dx + dy * dy + dz * dz;
        d2v[k] = d2;
        if (d2 < EXT2) act |= (1u << k);
    }

    // ONE slot allocation per active edge, issued before the barriers so the
    // L2 RMW latency hides under the ballot/prefix section.
    const int nact = __popc(act);
    int ti = 0;
    if (nact > 0) ti = atomicAdd(pcnt + d, nact);

    // ballots once; masks kept for the write phase
    unsigned long long kmask[KPTS];
    #pragma unroll
    for (int k = 0; k < KPTS; ++k) {
        kmask[k] = __ballot((act >> k) & 1u);
        if (lane == 0) s_wavecnt[k][wv] = __popcll(kmask[k]);
    }
    __syncthreads();

    if (tid < KPTS) {
        int o0 = 0;
        #pragma unroll
        for (int w = 0; w < 4; ++w) {
            s_woff[tid][w] = o0;
            o0 += s_wavecnt[tid][w];
        }
        s_base[tid] = (o0 > 0)
            ? atomicAdd(&cnt[(tid * NREP + rep) * CNT_STRIDE], o0) : 0;
    }
    __syncthreads();

    const unsigned long long lt = (lane == 63) ? 0x7fffffffffffffffull
                                               : ((1ull << lane) - 1ull);
    #pragma unroll
    for (int k = 0; k < KPTS; ++k) {
        const unsigned long long mask = kmask[k];
        if (mask == 0ull) continue;                 // wave-uniform skip
        if ((act >> k) & 1u) {
            const int rank = __popcll(mask & lt);
            const int idx  = s_base[k] + s_woff[k][wv] + rank;

            const int t = ti;                        // this pair's slot
            ++ti;
            const unsigned ey = (t < scap)
                ? (unsigned)((d * scap + t) * OUT_DIM)    // bit31 clear
                : (0x80000000u | (unsigned)d);            // overflow

            if (idx < SEG_CAP) {
                const float mk = 1.0f - sqrtf(d2v[k]) * INV_EXT;
                const unsigned mh =
                    (unsigned)__half_as_ushort(__float2half(mk));
                lists[(size_t)k * CAP + (size_t)rep * SEG_CAP + idx] =
                    make_uint2(((unsigned)s << 16) | mh, ey);
            } else if (!(ey & 0x80000000u)) {
                // list overflow (10x margin -> ~never): slot was allocated but
                // no K2 store will fill it; zero it so K3 never reads poison.
                uint* row = slots16 + (ey >> 1);
                #pragma unroll
                for (int j = 0; j < OUT_DIM / 2; ++j) row[j] = 0u;
            }
        }
    }
}

// ---------------------------------------------------------------------------
// K2: one wave per 2-pair chunk; lane = output channel. fp16 math with fp32
// accumulate. 2-deep pipeline: entries prefetched 2 chunks ahead, feat rows
// preloaded 1 chunk ahead. fp16 slot stores (even lanes store packed pairs).
// ---------------------------------------------------------------------------
__global__ __launch_bounds__(256) void pair_matmul(
    const uint*  __restrict__ featH,
    const float* __restrict__ W,       // [15][32][64] fp32
    const int*   __restrict__ cnt,
    const uint2* __restrict__ lists,
    float*       __restrict__ out,
    uint*        __restrict__ slots16)
{
    const int seg  = blockIdx.x % (KPTS * NREP);   // 0..239
    const int sub  = blockIdx.x / (KPTS * NREP);   // 0..SUBB-1
    const int k    = seg >> 4;
    const int rep  = seg & (NREP - 1);
    const int wv   = threadIdx.x >> 6;
    const int lane = threadIdx.x & 63;

    // W[k] column as packed fp16: wpk[j] = (W[k][2j][lane], W[k][2j+1][lane])
    uint wpk[16];
    #pragma unroll
    for (int j = 0; j < 16; ++j) {
        const float wa = W[k * (IN_DIM * OUT_DIM) + (2 * j)     * OUT_DIM + lane];
        const float wb = W[k * (IN_DIM * OUT_DIM) + (2 * j + 1) * OUT_DIM + lane];
        wpk[j] = pack2(wa, wb);
    }
    #pragma unroll
    for (int j = 0; j < 16; ++j)
        asm volatile("" : "+v"(wpk[j]));

    int n = cnt[seg * CNT_STRIDE];
    if (n > SEG_CAP) n = SEG_CAP;
    const uint2* __restrict__ list =
        lists + (size_t)k * CAP + (size_t)rep * SEG_CAP;

    const int widx    = sub * 4 + wv;              // 0..63
    const int stride2 = SUBB * 4 * 2;              // 128

    int base = widx * 2;
    if (base >= n) return;

    // chunk A entries (current) + chunk B entries (in flight)
    uint4 eeA = *reinterpret_cast<const uint4*>(list + base);
    const int bB0 = base + stride2;
    uint4 eeB = *reinterpret_cast<const uint4*>(list + (bB0 < n ? bB0 : 0));

    // decode A + preload feat A
    uint axA0 = RFL(eeA.x), ayA0 = RFL(eeA.y),
         axA1 = RFL(eeA.z), ayA1 = RFL(eeA.w);
    uint sA0 = axA0 >> 16; if (sA0 >= N_NODES) sA0 = 0;
    uint sA1 = axA1 >> 16; if (sA1 >= N_NODES) sA1 = 0;
    uint faA[16], fbA[16];
    {
        const uint* __restrict__ p0 = featH + sA0 * 16;
        const uint* __restrict__ p1 = featH + sA1 * 16;
        #pragma unroll
        for (int j = 0; j < 16; ++j) { faA[j] = p0[j]; fbA[j] = p1[j]; }
    }

    for (; base < n; base += stride2) {
        // prefetch entries 2 chunks ahead
        const int bC = base + 2 * stride2;
        const uint4 eeC = *reinterpret_cast<const uint4*>(list + (bC < n ? bC : 0));

        // decode B + issue feat-B loads (hide under A's dot chain)
        const uint axB0 = RFL(eeB.x), ayB0 = RFL(eeB.y),
                   axB1 = RFL(eeB.z), ayB1 = RFL(eeB.w);
        uint sB0 = axB0 >> 16; if (sB0 >= N_NODES) sB0 = 0;
        uint sB1 = axB1 >> 16; if (sB1 >= N_NODES) sB1 = 0;
        uint faB[16], fbB[16];
        {
            const uint* __restrict__ p0 = featH + sB0 * 16;
            const uint* __restrict__ p1 = featH + sB1 * 16;
            #pragma unroll
            for (int j = 0; j < 16; ++j) { faB[j] = p0[j]; fbB[j] = p1[j]; }
        }

        // compute chunk A: two independent dot2 chains
        float acc0 = 0.0f, acc1 = 0.0f;
        #pragma unroll
        for (int j = 0; j < 16; ++j) {
            acc0 = fdot2u(faA[j], wpk[j], acc0);
            acc1 = fdot2u(fbA[j], wpk[j], acc1);
        }
        const float m0 = h2f16(axA0);
        const float m1 = h2f16(axA1);
        const float r0 = m0 * acc0;
        const float r1 = m1 * acc1;
        const bool  two = (base + 1 < n);

        const float p0 = __shfl_xor(r0, 1);
        const float p1 = __shfl_xor(r1, 1);

        if (!(ayA0 & 0x80000000u)) {
            if (!(lane & 1))
                slots16[(ayA0 >> 1) + (lane >> 1)] = pack2(r0, p0);
        } else {
            atomicAdd(out + (size_t)(ayA0 & 0xffffu) * OUT_DIM + lane, r0);
        }
        if (two) {
            if (!(ayA1 & 0x80000000u)) {
                if (!(lane & 1))
                    slots16[(ayA1 >> 1) + (lane >> 1)] = pack2(r1, p1);
            } else {
                atomicAdd(out + (size_t)(ayA1 & 0xffffu) * OUT_DIM + lane, r1);
            }
        }

        // rotate pipeline B -> A
        axA0 = axB0; ayA0 = ayB0; axA1 = axB1; ayA1 = ayB1;
        #pragma unroll
        for (int j = 0; j < 16; ++j) { faA[j] = faB[j]; fbA[j] = fbB[j]; }
        eeB = eeC;
    }
}

// ---------------------------------------------------------------------------
// K3: 2 nodes per wave (all 64 lanes busy; lanes split 32/32), 6250 blocks.
// Sum fp16 slot rows (fp32 accumulate), add rare overflow atomics already in
// out, write float2.
// ---------------------------------------------------------------------------
__global__ __launch_bounds__(256) void node_reduce(
    const int*  __restrict__ pcnt,
    const uint* __restrict__ slots16,
    float*      __restrict__ out,
    const int scap)
{
    const int wv   = threadIdx.x >> 6;
    const int lane = threadIdx.x & 63;
    const int node = blockIdx.x * 8 + wv * 2 + (lane >> 5);  // 6250*8 = 50000
    const int l    = lane & 31;

    const int raw = pcnt[node];
    int deg = raw;
    if (deg > scap) deg = scap;

    const uint* __restrict__ sp =
        slots16 + (size_t)node * ((size_t)scap * 32) + l;

    float a0 = 0.0f, a1 = 0.0f, b0 = 0.0f, b1 = 0.0f;
    int j = 0;
    for (; j + 1 < deg; j += 2) {
        const uint u0 = sp[(size_t)j * 32];
        const uint u1 = sp[(size_t)(j + 1) * 32];
        a0 += h2f16(u0); a1 += h2f16(u0 >> 16);
        b0 += h2f16(u1); b1 += h2f16(u1 >> 16);
    }
    if (j < deg) {
        const uint u0 = sp[(size_t)j * 32];
        a0 += h2f16(u0); a1 += h2f16(u0 >> 16);
    }

    float o0 = a0 + b0;
    float o1 = a1 + b1;
    if (raw > scap) {   // overflow atomics already landed in (zeroed) out
        const float2 prev = ((const float2*)out)[(size_t)node * 32 + l];
        o0 += prev.x; o1 += prev.y;
    }
    ((float2*)out)[(size_t)node * 32 + l] = make_float2(o0, o1);
}

// ---------------------------------------------------------------------------
extern "C" void kernel_launch(void* const* d_in, const int* in_sizes, int n_in,
                              void* d_out, int out_size, void* d_ws, size_t ws_size,
                              hipStream_t stream)
{
    const float* pos  = (const float*)d_in[0];   // [50000,3]
    const float* feat = (const float*)d_in[1];   // [50000,32]
    const float* kp   = (const float*)d_in[2];   // [15,3]
    const float* W    = (const float*)d_in[3];   // [15,32,64]
    const int* esrc   = (const int*)d_in[4];     // [800000]
    const int* edst   = (const int*)d_in[5];     // [800000]
    float* out        = (float*)d_out;           // [50000,64]

    int*   cnt     = (int*)d_ws;
    int*   pcnt    = (int*)((char*)d_ws + PCNT_OFF);
    uint*  featH   = (uint*)((char*)d_ws + FEATH_OFF);
    uint2* lists   = (uint2*)((char*)d_ws + LIST_OFF);
    uint*  slots16 = (uint*)((char*)d_ws + SLOT_OFF);

    // slot capacity from available workspace (fp16 rows: 128B each)
    const size_t layer_bytes = (size_t)N_NODES * OUT_DIM * 2;   // 6.4MB
    int scap = 0;
    if (ws_size >= (size_t)SLOT_OFF + layer_bytes) {
        scap = (int)((ws_size - (size_t)SLOT_OFF) / layer_bytes);
        if (scap > SCAP_MAX) scap = SCAP_MAX;
    }

    hipMemsetAsync(d_ws, 0, 262144, stream);   // counters + pcnt

    geom_compact<<<K1_BLOCKS, 256, 0, stream>>>(pos, feat, kp, esrc, edst,
                                                cnt, pcnt, lists, featH,
                                                (float4*)out, slots16, scap);
    pair_matmul<<<SUBB * KPTS * NREP, 256, 0, stream>>>(featH, W, cnt, lists,
                                                        out, slots16);
    if (scap > 0)
        node_reduce<<<N_NODES / 8, 256, 0, stream>>>(pcnt, slots16, out, scap);
}

// Round 9
// 114.595 us; speedup vs baseline: 4.8970x; 1.1044x over previous
//
#include <hip/hip_runtime.h>
#include <hip/hip_fp16.h>

#define N_NODES 50000
#define N_EDGES 800000
#define KPTS 15
#define IN_DIM 32
#define OUT_DIM 64
#define KP_EXTENT 0.6f
#define INV_EXT (1.0f / KP_EXTENT)
#define EXT2 (KP_EXTENT * KP_EXTENT)

#define CAP 131072            // per-k total list capacity
#define NREP 16               // counter/list replicas per k
#define SEG_CAP (CAP / NREP)  // 8192 entries per (k,replica) segment
#define CNT_STRIDE 32         // ints: 128B between counters
#define K1_BLOCKS (N_EDGES / 256)   // 3125
#define SUBB 8                // blocks per segment in K2 -> 1920 blocks
#define WPS (SUBB * 4)        // waves per segment = 32

// ws layout (ws = 256 MiB measured):
//   [0,      32768)   240 replica counters (stride 128B)
//   [32768, 232768)   pcnt[50000] slot counters
//   [1MB,   1MB+3.2M) featH[50000][32] packed fp16 (uint per 2 channels)
//   [8MB,   23.7MB)   15 lists of CAP uint2 (x=(src<<16)|fp16(m), y=slot
//                     fp16-element offset, or 0x80000000|d overflow sentinel)
//   [32MB,  134.4MB)  slots16[50000][scap][64] fp16 partial rows (packed uint)
#define PCNT_OFF 32768
#define FEATH_OFF (1u << 20)
#define LIST_OFF  (8u << 20)
#define SLOT_OFF  (32u << 20)
#define SCAP_MAX 16

typedef unsigned int uint;
typedef _Float16 f16x8 __attribute__((ext_vector_type(8)));
typedef float f32x4 __attribute__((ext_vector_type(4)));

union FU { uint u[4]; f16x8 h; };

static __device__ __forceinline__ float h2f16(uint u) {
    return __half2float(__ushort_as_half((unsigned short)(u & 0xffffu)));
}
static __device__ __forceinline__ uint pack2(float lo, float hi) {
    return (uint)__half_as_ushort(__float2half_rn(lo))
         | ((uint)__half_as_ushort(__float2half_rn(hi)) << 16);
}

// ---------------------------------------------------------------------------
// K1: geometry + ballot compaction into per-(k,replica) segments (unchanged
// from round 8: ballots once, one pcnt atomic per active edge issued early,
// wave-uniform skip of empty k-iterations). Also zeroes `out` and converts
// feat -> packed fp16.
// ---------------------------------------------------------------------------
__global__ __launch_bounds__(256) void geom_compact(
    const float* __restrict__ pos,
    const float* __restrict__ feat,
    const float* __restrict__ kp,
    const int*   __restrict__ esrc,
    const int*   __restrict__ edst,
    int*         __restrict__ cnt,
    int*         __restrict__ pcnt,
    uint2*       __restrict__ lists,
    uint*        __restrict__ featH,   // 800000 uints
    float4*      __restrict__ outz,    // out viewed as float4[800000]
    uint*        __restrict__ slots16, // for rare list-overflow zero-fill
    const int scap)
{
    __shared__ int s_wavecnt[KPTS][4];
    __shared__ int s_woff[KPTS][4];
    __shared__ int s_base[KPTS];

    const int tid  = threadIdx.x;
    const int wv   = tid >> 6;
    const int lane = tid & 63;
    const int rep  = blockIdx.x & (NREP - 1);

    const int e = blockIdx.x * 256 + tid;      // grid covers E exactly

    outz[e] = make_float4(0.0f, 0.0f, 0.0f, 0.0f);
    {
        const float2 fv = ((const float2*)feat)[e];   // 800000 = 50000*32/2
        featH[e] = pack2(fv.x, fv.y);
    }

    const int s = esrc[e];
    const int d = edst[e];

    const float yx = pos[s * 3 + 0] - pos[d * 3 + 0];
    const float yy = pos[s * 3 + 1] - pos[d * 3 + 1];
    const float yz = pos[s * 3 + 2] - pos[d * 3 + 2];

    float d2v[KPTS];
    unsigned act = 0;
    #pragma unroll
    for (int k = 0; k < KPTS; ++k) {
        const float dx = yx - kp[k * 3 + 0];
        const float dy = yy - kp[k * 3 + 1];
        const float dz = yz - kp[k * 3 + 2];
        const float d2 = dx * dx + dy * dy + dz * dz;
        d2v[k] = d2;
        if (d2 < EXT2) act |= (1u << k);
    }

    // ONE slot allocation per active edge, issued early (latency hidden)
    const int nact = __popc(act);
    int ti = 0;
    if (nact > 0) ti = atomicAdd(pcnt + d, nact);

    unsigned long long kmask[KPTS];
    #pragma unroll
    for (int k = 0; k < KPTS; ++k) {
        kmask[k] = __ballot((act >> k) & 1u);
        if (lane == 0) s_wavecnt[k][wv] = __popcll(kmask[k]);
    }
    __syncthreads();

    if (tid < KPTS) {
        int o0 = 0;
        #pragma unroll
        for (int w = 0; w < 4; ++w) {
            s_woff[tid][w] = o0;
            o0 += s_wavecnt[tid][w];
        }
        s_base[tid] = (o0 > 0)
            ? atomicAdd(&cnt[(tid * NREP + rep) * CNT_STRIDE], o0) : 0;
    }
    __syncthreads();

    const unsigned long long lt = (lane == 63) ? 0x7fffffffffffffffull
                                               : ((1ull << lane) - 1ull);
    #pragma unroll
    for (int k = 0; k < KPTS; ++k) {
        const unsigned long long mask = kmask[k];
        if (mask == 0ull) continue;                 // wave-uniform skip
        if ((act >> k) & 1u) {
            const int rank = __popcll(mask & lt);
            const int idx  = s_base[k] + s_woff[k][wv] + rank;

            const int t = ti;                        // this pair's slot
            ++ti;
            const unsigned ey = (t < scap)
                ? (unsigned)((d * scap + t) * OUT_DIM)    // bit31 clear
                : (0x80000000u | (unsigned)d);            // overflow

            if (idx < SEG_CAP) {
                const float mk = 1.0f - sqrtf(d2v[k]) * INV_EXT;
                const unsigned mh =
                    (unsigned)__half_as_ushort(__float2half(mk));
                lists[(size_t)k * CAP + (size_t)rep * SEG_CAP + idx] =
                    make_uint2(((unsigned)s << 16) | mh, ey);
            } else if (!(ey & 0x80000000u)) {
                // list overflow (~never): zero the allocated slot row
                uint* row = slots16 + (ey >> 1);
                #pragma unroll
                for (int j = 0; j < OUT_DIM / 2; ++j) row[j] = 0u;
            }
        }
    }
}

// ---------------------------------------------------------------------------
// K2: MFMA version. One wave-step = 16 pairs: each lane loads the entry of
// row (lane&15), vector-gathers 16B of that feat row into the A-fragment
// (lane layout: row=lane&15, k-halves=(lane>>4)*8..+7), and 4 stationary
// W n-tiles (B) give all 16x64 outputs via 4 x mfma_f32_16x16x32_f16.
// NOTE: the intra-group k ordering cancels between A and B (same bijection
// on both sides), so only the row/col conventions matter; C/D layout is
// col=lane&15, row=(lane>>4)*4+reg (HW-verified). Rows are scaled by m and
// scatter-stored as fp16 to precomputed slots; pads use sentinel 0xFFFFFFFF.
// ---------------------------------------------------------------------------
__global__ __launch_bounds__(256) void pair_matmul(
    const uint*  __restrict__ featH,
    const float* __restrict__ W,       // [15][32][64] fp32
    const int*   __restrict__ cnt,
    const uint2* __restrict__ lists,
    float*       __restrict__ out,
    uint*        __restrict__ slots16)
{
    const int seg  = blockIdx.x % (KPTS * NREP);   // 0..239
    const int sub  = blockIdx.x / (KPTS * NREP);   // 0..SUBB-1
    const int k    = seg >> 4;
    const int rep  = seg & (NREP - 1);
    const int wv   = threadIdx.x >> 6;
    const int lane = threadIdx.x & 63;
    const int col  = lane & 15;                    // A-row / B-col-in-tile
    const int grp  = lane >> 4;                    // k-group of 8 halves

    // B preload: 4 n-tiles of W[k], packed fp16, pinned in 16 VGPRs
    uint bu[4][4];
    const float* __restrict__ Wk = W + k * (IN_DIM * OUT_DIM);
    #pragma unroll
    for (int t = 0; t < 4; ++t) {
        #pragma unroll
        for (int j = 0; j < 4; ++j) {
            const int kk = grp * 8 + 2 * j;
            const float wa = Wk[kk * OUT_DIM + t * 16 + col];
            const float wb = Wk[(kk + 1) * OUT_DIM + t * 16 + col];
            bu[t][j] = pack2(wa, wb);
        }
    }
    #pragma unroll
    for (int t = 0; t < 4; ++t)
        #pragma unroll
        for (int j = 0; j < 4; ++j)
            asm volatile("" : "+v"(bu[t][j]));

    int n = cnt[seg * CNT_STRIDE];
    if (n > SEG_CAP) n = SEG_CAP;
    const uint2* __restrict__ list =
        lists + (size_t)k * CAP + (size_t)rep * SEG_CAP;
    const int nsteps = (n + 15) >> 4;

    const int w = sub * 4 + wv;                    // 0..WPS-1
    for (int s = w; s < nsteps; s += WPS) {
        const int pi = s * 16 + col;               // this lane's A-row pair
        const uint2 ent = (pi < n) ? list[pi] : make_uint2(0u, 0xFFFFFFFFu);

        // A gather: 16B of feat row `src`, k-halves grp*8..+7
        const uint src = ent.x >> 16;              // pad -> 0 (safe)
        FU A;
        {
            const uint* __restrict__ fp = featH + src * 16 + grp * 4;
            #pragma unroll
            for (int j = 0; j < 4; ++j) A.u[j] = fp[j];
        }
        const float mym = h2f16(ent.x);            // m of row `col` (pad -> 0)

        f32x4 C0 = {0,0,0,0}, C1 = {0,0,0,0}, C2 = {0,0,0,0}, C3 = {0,0,0,0};
        {
            FU b0, b1, b2, b3;
            #pragma unroll
            for (int j = 0; j < 4; ++j) {
                b0.u[j] = bu[0][j]; b1.u[j] = bu[1][j];
                b2.u[j] = bu[2][j]; b3.u[j] = bu[3][j];
            }
            C0 = __builtin_amdgcn_mfma_f32_16x16x32_f16(A.h, b0.h, C0, 0, 0, 0);
            C1 = __builtin_amdgcn_mfma_f32_16x16x32_f16(A.h, b1.h, C1, 0, 0, 0);
            C2 = __builtin_amdgcn_mfma_f32_16x16x32_f16(A.h, b2.h, C2, 0, 0, 0);
            C3 = __builtin_amdgcn_mfma_f32_16x16x32_f16(A.h, b3.h, C3, 0, 0, 0);
        }

        // stores: lane covers rows r = grp*4+i, cols t*16+col
        #pragma unroll
        for (int i = 0; i < 4; ++i) {
            const int r = grp * 4 + i;
            const float mr = __shfl(mym, r);           // m of row r
            const uint  er = (uint)__shfl((int)ent.y, r);
            if (er == 0xFFFFFFFFu) continue;           // pad row
            const float v0 = mr * C0[i];
            const float v1 = mr * C1[i];
            const float v2 = mr * C2[i];
            const float v3 = mr * C3[i];
            if (!(er & 0x80000000u)) {
                __half* __restrict__ sp = (__half*)slots16 + (size_t)er + col;
                sp[0]  = __float2half_rn(v0);
                sp[16] = __float2half_rn(v1);
                sp[32] = __float2half_rn(v2);
                sp[48] = __float2half_rn(v3);
            } else {
                float* __restrict__ op = out + (size_t)(er & 0xffffu) * OUT_DIM + col;
                atomicAdd(op +  0, v0);
                atomicAdd(op + 16, v1);
                atomicAdd(op + 32, v2);
                atomicAdd(op + 48, v3);
            }
        }
    }
}

// ---------------------------------------------------------------------------
// K3: 2 nodes per wave (all 64 lanes busy), 6250 blocks. Sum fp16 slot rows
// (fp32 accumulate), add rare overflow atomics already in out, write float2.
// ---------------------------------------------------------------------------
__global__ __launch_bounds__(256) void node_reduce(
    const int*  __restrict__ pcnt,
    const uint* __restrict__ slots16,
    float*      __restrict__ out,
    const int scap)
{
    const int wv   = threadIdx.x >> 6;
    const int lane = threadIdx.x & 63;
    const int node = blockIdx.x * 8 + wv * 2 + (lane >> 5);  // 6250*8 = 50000
    const int l    = lane & 31;

    const int raw = pcnt[node];
    int deg = raw;
    if (deg > scap) deg = scap;

    const uint* __restrict__ sp =
        slots16 + (size_t)node * ((size_t)scap * 32) + l;

    float a0 = 0.0f, a1 = 0.0f, b0 = 0.0f, b1 = 0.0f;
    int j = 0;
    for (; j + 1 < deg; j += 2) {
        const uint u0 = sp[(size_t)j * 32];
        const uint u1 = sp[(size_t)(j + 1) * 32];
        a0 += h2f16(u0); a1 += h2f16(u0 >> 16);
        b0 += h2f16(u1); b1 += h2f16(u1 >> 16);
    }
    if (j < deg) {
        const uint u0 = sp[(size_t)j * 32];
        a0 += h2f16(u0); a1 += h2f16(u0 >> 16);
    }

    float o0 = a0 + b0;
    float o1 = a1 + b1;
    if (raw > scap) {   // overflow atomics already landed in (zeroed) out
        const float2 prev = ((const float2*)out)[(size_t)node * 32 + l];
        o0 += prev.x; o1 += prev.y;
    }
    ((float2*)out)[(size_t)node * 32 + l] = make_float2(o0, o1);
}

// ---------------------------------------------------------------------------
extern "C" void kernel_launch(void* const* d_in, const int* in_sizes, int n_in,
                              void* d_out, int out_size, void* d_ws, size_t ws_size,
                              hipStream_t stream)
{
    const float* pos  = (const float*)d_in[0];   // [50000,3]
    const float* feat = (const float*)d_in[1];   // [50000,32]
    const float* kp   = (const float*)d_in[2];   // [15,3]
    const float* W    = (const float*)d_in[3];   // [15,32,64]
    const int* esrc   = (const int*)d_in[4];     // [800000]
    const int* edst   = (const int*)d_in[5];     // [800000]
    float* out        = (float*)d_out;           // [50000,64]

    int*   cnt     = (int*)d_ws;
    int*   pcnt    = (int*)((char*)d_ws + PCNT_OFF);
    uint*  featH   = (uint*)((char*)d_ws + FEATH_OFF);
    uint2* lists   = (uint2*)((char*)d_ws + LIST_OFF);
    uint*  slots16 = (uint*)((char*)d_ws + SLOT_OFF);

    // slot capacity from available workspace (fp16 rows: 128B each)
    const size_t layer_bytes = (size_t)N_NODES * OUT_DIM * 2;   // 6.4MB
    int scap = 0;
    if (ws_size >= (size_t)SLOT_OFF + layer_bytes) {
        scap = (int)((ws_size - (size_t)SLOT_OFF) / layer_bytes);
        if (scap > SCAP_MAX) scap = SCAP_MAX;
    }

    hipMemsetAsync(d_ws, 0, 262144, stream);   // counters + pcnt

    geom_compact<<<K1_BLOCKS, 256, 0, stream>>>(pos, feat, kp, esrc, edst,
                                                cnt, pcnt, lists, featH,
                                                (float4*)out, slots16, scap);
    pair_matmul<<<SUBB * KPTS * NREP, 256, 0, stream>>>(featH, W, cnt, lists,
                                                        out, slots16);
    if (scap > 0)
        node_reduce<<<N_NODES / 8, 256, 0, stream>>>(pcnt, slots16, out, scap);
}

// Round 10
// 113.834 us; speedup vs baseline: 4.9297x; 1.0067x over previous
//
#include <hip/hip_runtime.h>
#include <hip/hip_fp16.h>

#define N_NODES 50000
#define N_EDGES 800000
#define KPTS 15
#define IN_DIM 32
#define OUT_DIM 64
#define KP_EXTENT 0.6f
#define INV_EXT (1.0f / KP_EXTENT)
#define EXT2 (KP_EXTENT * KP_EXTENT)

#define CAP 131072            // per-k total list capacity
#define NREP 16               // counter/list replicas per k
#define SEG_CAP (CAP / NREP)  // 8192 entries per (k,replica) segment
#define CNT_STRIDE 32         // ints: 128B between counters
#define K1_BLOCKS (N_EDGES / 256)   // 3125
#define SUBB 4                // blocks per segment in K2 -> 960 blocks
#define WPS (SUBB * 4)        // waves per segment = 16

// ws layout (ws = 256 MiB measured):
//   [0,      32768)   240 replica counters (stride 128B)
//   [32768, 232768)   pcnt[50000] slot counters
//   [262144, 323584)  WH[15][16][64] packed-fp16 W (uint per k-pair) 61.4KB
//   [1MB,   1MB+3.2M) featH[50000][32] packed fp16 (uint per 2 channels)
//   [8MB,   23.7MB)   15 lists of CAP uint2 (x=(src<<16)|fp16(m), y=slot
//                     fp16-element offset, or 0x80000000|d overflow sentinel)
//   [32MB,  134.4MB)  slots16[50000][scap][64] fp16 partial rows (packed uint)
#define PCNT_OFF 32768
#define WH_OFF   262144
#define FEATH_OFF (1u << 20)
#define LIST_OFF  (8u << 20)
#define SLOT_OFF  (32u << 20)
#define SCAP_MAX 16

typedef unsigned int uint;
typedef _Float16 f16x8 __attribute__((ext_vector_type(8)));
typedef float f32x4 __attribute__((ext_vector_type(4)));

union FU { uint u[4]; f16x8 h; };
union HU { unsigned short us; _Float16 h; };

static __device__ __forceinline__ float h2f16(uint u) {
    return __half2float(__ushort_as_half((unsigned short)(u & 0xffffu)));
}
static __device__ __forceinline__ uint pack2(float lo, float hi) {
    return (uint)__half_as_ushort(__float2half_rn(lo))
         | ((uint)__half_as_ushort(__float2half_rn(hi)) << 16);
}

// ---------------------------------------------------------------------------
// K1: geometry + ballot compaction into per-(k,replica) segments (round-8
// structure: ballots once, one pcnt atomic per active edge issued early,
// wave-uniform skip). Also zeroes `out`, converts feat -> packed fp16, and
// NEW: converts W -> packed fp16 (threads e<15360, one uint each).
// ---------------------------------------------------------------------------
__global__ __launch_bounds__(256) void geom_compact(
    const float* __restrict__ pos,
    const float* __restrict__ feat,
    const float* __restrict__ kp,
    const float* __restrict__ W,       // [15][32][64] fp32
    const int*   __restrict__ esrc,
    const int*   __restrict__ edst,
    int*         __restrict__ cnt,
    int*         __restrict__ pcnt,
    uint2*       __restrict__ lists,
    uint*        __restrict__ featH,   // 800000 uints
    uint*        __restrict__ WH,      // 15360 uints
    float4*      __restrict__ outz,    // out viewed as float4[800000]
    uint*        __restrict__ slots16, // for rare list-overflow zero-fill
    const int scap)
{
    __shared__ int s_wavecnt[KPTS][4];
    __shared__ int s_woff[KPTS][4];
    __shared__ int s_base[KPTS];

    const int tid  = threadIdx.x;
    const int wv   = tid >> 6;
    const int lane = tid & 63;
    const int rep  = blockIdx.x & (NREP - 1);

    const int e = blockIdx.x * 256 + tid;      // grid covers E exactly

    outz[e] = make_float4(0.0f, 0.0f, 0.0f, 0.0f);
    {
        const float2 fv = ((const float2*)feat)[e];   // 800000 = 50000*32/2
        featH[e] = pack2(fv.x, fv.y);
    }
    if (e < KPTS * (IN_DIM / 2) * OUT_DIM) {          // 15360
        // WH[e], e = k*1024 + j*64 + col  ->  pack(W[k][2j][col], W[k][2j+1][col])
        const int c  = e & 63;
        const int f0 = 2 * e - c;                     // k*2048 + 2j*64 + col
        WH[e] = pack2(W[f0], W[f0 + 64]);
    }

    const int s = esrc[e];
    const int d = edst[e];

    const float yx = pos[s * 3 + 0] - pos[d * 3 + 0];
    const float yy = pos[s * 3 + 1] - pos[d * 3 + 1];
    const float yz = pos[s * 3 + 2] - pos[d * 3 + 2];

    float d2v[KPTS];
    unsigned act = 0;
    #pragma unroll
    for (int k = 0; k < KPTS; ++k) {
        const float dx = yx - kp[k * 3 + 0];
        const float dy = yy - kp[k * 3 + 1];
        const float dz = yz - kp[k * 3 + 2];
        const float d2 = dx * dx + dy * dy + dz * dz;
        d2v[k] = d2;
        if (d2 < EXT2) act |= (1u << k);
    }

    // ONE slot allocation per active edge, issued early (latency hidden)
    const int nact = __popc(act);
    int ti = 0;
    if (nact > 0) ti = atomicAdd(pcnt + d, nact);

    unsigned long long kmask[KPTS];
    #pragma unroll
    for (int k = 0; k < KPTS; ++k) {
        kmask[k] = __ballot((act >> k) & 1u);
        if (lane == 0) s_wavecnt[k][wv] = __popcll(kmask[k]);
    }
    __syncthreads();

    if (tid < KPTS) {
        int o0 = 0;
        #pragma unroll
        for (int w = 0; w < 4; ++w) {
            s_woff[tid][w] = o0;
            o0 += s_wavecnt[tid][w];
        }
        s_base[tid] = (o0 > 0)
            ? atomicAdd(&cnt[(tid * NREP + rep) * CNT_STRIDE], o0) : 0;
    }
    __syncthreads();

    const unsigned long long lt = (lane == 63) ? 0x7fffffffffffffffull
                                               : ((1ull << lane) - 1ull);
    #pragma unroll
    for (int k = 0; k < KPTS; ++k) {
        const unsigned long long mask = kmask[k];
        if (mask == 0ull) continue;                 // wave-uniform skip
        if ((act >> k) & 1u) {
            const int rank = __popcll(mask & lt);
            const int idx  = s_base[k] + s_woff[k][wv] + rank;

            const int t = ti;                        // this pair's slot
            ++ti;
            const unsigned ey = (t < scap)
                ? (unsigned)((d * scap + t) * OUT_DIM)    // bit31 clear
                : (0x80000000u | (unsigned)d);            // overflow

            if (idx < SEG_CAP) {
                const float mk = 1.0f - sqrtf(d2v[k]) * INV_EXT;
                const unsigned mh =
                    (unsigned)__half_as_ushort(__float2half(mk));
                lists[(size_t)k * CAP + (size_t)rep * SEG_CAP + idx] =
                    make_uint2(((unsigned)s << 16) | mh, ey);
            } else if (!(ey & 0x80000000u)) {
                // list overflow (~never): zero the allocated slot row
                uint* row = slots16 + (ey >> 1);
                #pragma unroll
                for (int j = 0; j < OUT_DIM / 2; ++j) row[j] = 0u;
            }
        }
    }
}

// ---------------------------------------------------------------------------
// K2: MFMA, one wave-step = 16 pairs. A-fragment (row=lane&15,
// k-halves=(lane>>4)*8..+7) is PRE-SCALED by the row's m in fp16
// (m*(f.w) == (m*f).w; the lane's own ent.x carries its row's m), so the
// epilogue has no shfl/mul. B: 4 stationary n-tiles from the fp16-packed WH
// (16 coalesced uint loads). SUBB=4 -> ~3.3 steps/wave amortizes the
// prologue; next-step entries prefetched before the MFMA cluster.
// C/D layout: col=lane&15, row=(lane>>4)*4+reg (HW-verified).
// ---------------------------------------------------------------------------
__global__ __launch_bounds__(256) void pair_matmul(
    const uint*  __restrict__ featH,
    const uint*  __restrict__ WH,      // [15][16][64] packed fp16
    const int*   __restrict__ cnt,
    const uint2* __restrict__ lists,
    float*       __restrict__ out,
    uint*        __restrict__ slots16)
{
    const int seg  = blockIdx.x % (KPTS * NREP);   // 0..239
    const int sub  = blockIdx.x / (KPTS * NREP);   // 0..SUBB-1
    const int k    = seg >> 4;
    const int rep  = seg & (NREP - 1);
    const int wv   = threadIdx.x >> 6;
    const int lane = threadIdx.x & 63;
    const int col  = lane & 15;                    // A-row / B-col-in-tile
    const int grp  = lane >> 4;                    // k-group of 8 halves

    // B preload: bu[t][j] = WH[k*1024 + (grp*4+j)*64 + t*16 + col]
    uint bu[4][4];
    const uint* __restrict__ Whk = WH + k * 1024 + grp * 256 + col;
    #pragma unroll
    for (int t = 0; t < 4; ++t)
        #pragma unroll
        for (int j = 0; j < 4; ++j)
            bu[t][j] = Whk[j * 64 + t * 16];
    #pragma unroll
    for (int t = 0; t < 4; ++t)
        #pragma unroll
        for (int j = 0; j < 4; ++j)
            asm volatile("" : "+v"(bu[t][j]));

    int n = cnt[seg * CNT_STRIDE];
    if (n > SEG_CAP) n = SEG_CAP;
    const uint2* __restrict__ list =
        lists + (size_t)k * CAP + (size_t)rep * SEG_CAP;
    const int nsteps = (n + 15) >> 4;

    int s = sub * 4 + wv;                          // 0..WPS-1
    if (s >= nsteps) return;

    // stage 0: entries + A gather for first step
    uint2 ent;
    {
        const int pi = s * 16 + col;
        ent = (pi < n) ? list[pi] : make_uint2(0u, 0xFFFFFFFFu);
    }
    FU A;
    {
        const uint* __restrict__ fp = featH + (ent.x >> 16) * 16 + grp * 4;
        #pragma unroll
        for (int j = 0; j < 4; ++j) A.u[j] = fp[j];
    }

    while (true) {
        // prefetch next step's entries (overlaps the MFMA cluster below)
        const int s2 = s + WPS;
        uint2 entN = make_uint2(0u, 0xFFFFFFFFu);
        if (s2 < nsteps) {
            const int pi2 = s2 * 16 + col;
            if (pi2 < n) entN = list[pi2];
        }

        // pre-scale A by this row's m (fp16); pad rows have m=0
        HU mu; mu.us = (unsigned short)(ent.x & 0xffffu);
        const f16x8 ms = {mu.h, mu.h, mu.h, mu.h, mu.h, mu.h, mu.h, mu.h};
        FU As; As.h = A.h * ms;

        f32x4 C0 = {0,0,0,0}, C1 = {0,0,0,0}, C2 = {0,0,0,0}, C3 = {0,0,0,0};
        {
            FU b0, b1, b2, b3;
            #pragma unroll
            for (int j = 0; j < 4; ++j) {
                b0.u[j] = bu[0][j]; b1.u[j] = bu[1][j];
                b2.u[j] = bu[2][j]; b3.u[j] = bu[3][j];
            }
            C0 = __builtin_amdgcn_mfma_f32_16x16x32_f16(As.h, b0.h, C0, 0, 0, 0);
            C1 = __builtin_amdgcn_mfma_f32_16x16x32_f16(As.h, b1.h, C1, 0, 0, 0);
            C2 = __builtin_amdgcn_mfma_f32_16x16x32_f16(As.h, b2.h, C2, 0, 0, 0);
            C3 = __builtin_amdgcn_mfma_f32_16x16x32_f16(As.h, b3.h, C3, 0, 0, 0);
        }

        // stores: lane covers rows r = grp*4+i, cols t*16+col (already m-scaled)
        #pragma unroll
        for (int i = 0; i < 4; ++i) {
            const int r = grp * 4 + i;
            const uint er = (uint)__shfl((int)ent.y, r);
            if (er == 0xFFFFFFFFu) continue;           // pad row
            if (!(er & 0x80000000u)) {
                __half* __restrict__ sp = (__half*)slots16 + (size_t)er + col;
                sp[0]  = __float2half_rn(C0[i]);
                sp[16] = __float2half_rn(C1[i]);
                sp[32] = __float2half_rn(C2[i]);
                sp[48] = __float2half_rn(C3[i]);
            } else {
                float* __restrict__ op = out + (size_t)(er & 0xffffu) * OUT_DIM + col;
                atomicAdd(op +  0, C0[i]);
                atomicAdd(op + 16, C1[i]);
                atomicAdd(op + 32, C2[i]);
                atomicAdd(op + 48, C3[i]);
            }
        }

        if (s2 >= nsteps) break;
        s = s2;
        ent = entN;
        const uint* __restrict__ fp = featH + (ent.x >> 16) * 16 + grp * 4;
        #pragma unroll
        for (int j = 0; j < 4; ++j) A.u[j] = fp[j];
    }
}

// ---------------------------------------------------------------------------
// K3: 2 nodes per wave (all 64 lanes busy), 6250 blocks. Sum fp16 slot rows
// (fp32 accumulate), add rare overflow atomics already in out, write float2.
// ---------------------------------------------------------------------------
__global__ __launch_bounds__(256) void node_reduce(
    const int*  __restrict__ pcnt,
    const uint* __restrict__ slots16,
    float*      __restrict__ out,
    const int scap)
{
    const int wv   = threadIdx.x >> 6;
    const int lane = threadIdx.x & 63;
    const int node = blockIdx.x * 8 + wv * 2 + (lane >> 5);  // 6250*8 = 50000
    const int l    = lane & 31;

    const int raw = pcnt[node];
    int deg = raw;
    if (deg > scap) deg = scap;

    const uint* __restrict__ sp =
        slots16 + (size_t)node * ((size_t)scap * 32) + l;

    float a0 = 0.0f, a1 = 0.0f, b0 = 0.0f, b1 = 0.0f;
    int j = 0;
    for (; j + 1 < deg; j += 2) {
        const uint u0 = sp[(size_t)j * 32];
        const uint u1 = sp[(size_t)(j + 1) * 32];
        a0 += h2f16(u0); a1 += h2f16(u0 >> 16);
        b0 += h2f16(u1); b1 += h2f16(u1 >> 16);
    }
    if (j < deg) {
        const uint u0 = sp[(size_t)j * 32];
        a0 += h2f16(u0); a1 += h2f16(u0 >> 16);
    }

    float o0 = a0 + b0;
    float o1 = a1 + b1;
    if (raw > scap) {   // overflow atomics already landed in (zeroed) out
        const float2 prev = ((const float2*)out)[(size_t)node * 32 + l];
        o0 += prev.x; o1 += prev.y;
    }
    ((float2*)out)[(size_t)node * 32 + l] = make_float2(o0, o1);
}

// ---------------------------------------------------------------------------
extern "C" void kernel_launch(void* const* d_in, const int* in_sizes, int n_in,
                              void* d_out, int out_size, void* d_ws, size_t ws_size,
                              hipStream_t stream)
{
    const float* pos  = (const float*)d_in[0];   // [50000,3]
    const float* feat = (const float*)d_in[1];   // [50000,32]
    const float* kp   = (const float*)d_in[2];   // [15,3]
    const float* W    = (const float*)d_in[3];   // [15,32,64]
    const int* esrc   = (const int*)d_in[4];     // [800000]
    const int* edst   = (const int*)d_in[5];     // [800000]
    float* out        = (float*)d_out;           // [50000,64]

    int*   cnt     = (int*)d_ws;
    int*   pcnt    = (int*)((char*)d_ws + PCNT_OFF);
    uint*  WH      = (uint*)((char*)d_ws + WH_OFF);
    uint*  featH   = (uint*)((char*)d_ws + FEATH_OFF);
    uint2* lists   = (uint2*)((char*)d_ws + LIST_OFF);
    uint*  slots16 = (uint*)((char*)d_ws + SLOT_OFF);

    // slot capacity from available workspace (fp16 rows: 128B each)
    const size_t layer_bytes = (size_t)N_NODES * OUT_DIM * 2;   // 6.4MB
    int scap = 0;
    if (ws_size >= (size_t)SLOT_OFF + layer_bytes) {
        scap = (int)((ws_size - (size_t)SLOT_OFF) / layer_bytes);
        if (scap > SCAP_MAX) scap = SCAP_MAX;
    }

    hipMemsetAsync(d_ws, 0, 262144, stream);   // counters + pcnt

    geom_compact<<<K1_BLOCKS, 256, 0, stream>>>(pos, feat, kp, W, esrc, edst,
                                                cnt, pcnt, lists, featH, WH,
                                                (float4*)out, slots16, scap);
    pair_matmul<<<SUBB * KPTS * NREP, 256, 0, stream>>>(featH, WH, cnt, lists,
                                                        out, slots16);
    if (scap > 0)
        node_reduce<<<N_NODES / 8, 256, 0, stream>>>(pcnt, slots16, out, scap);
}